// Round 7
// baseline (2235.876 us; speedup 1.0000x reference)
//
#include <hip/hip_runtime.h>
#include <hip/hip_bf16.h>
#include <cstdint>
#include <cstddef>

// Problem constants (fixed by reference)
#define B_    8
#define T_    256
#define D_    512
#define W_    32
#define L_    4
#define A_    6
#define H_    8
#define DH_   64
#define NWIN  (B_*T_)            // 2048 windows
#define NTOK  (NWIN*W_)          // 65536 token rows
#define FROWS 2176               // layer-0 qkv factor rows
#define SMALL (NWIN*D_)          // 2048x512 compact buffers (elems)

typedef __hip_bfloat16 bf16;
using bf16x8 = __attribute__((ext_vector_type(8))) short;   // MFMA A/B frag (4 VGPR)
using f32x4  = __attribute__((ext_vector_type(4))) float;   // 16x16 MFMA C/D frag
using f32x16 = __attribute__((ext_vector_type(16))) float;  // 32x32 MFMA C/D frag

// ---- memory plan (bytes): bf16-only residual stream ----------------------
#define XB_BYTES  ((size_t)NTOK * D_ * 2)     // 64 MiB bf16 residual master
#define WQ_ELEMS  ((size_t)L_ * 3*D_*D_)
#define WO_ELEMS  ((size_t)L_ * D_*D_)
#define W1_ELEMS  ((size_t)L_ * 4*D_*D_)
#define W2_ELEMS  ((size_t)L_ * 4*D_*D_)
#define WB_BYTES  ((WQ_ELEMS + WO_ELEMS + W1_ELEMS + W2_ELEMS) * 2)
#define FB_ELEMS  ((size_t)FROWS * D_)        // layer-0 factor input
#define QF_ELEMS  ((size_t)FROWS * 3*D_)      // layer-0 factor qkv
#define PPB_ELEMS ((size_t)W_ * 3*D_)         // fp32 pos+bias table
#define SCR_BYTES ((size_t)NTOK * 2560 * 2)   // qkv+ctx / h (+y unused)
#define TOTAL_BYTES (XB_BYTES + WB_BYTES + (FB_ELEMS + QF_ELEMS)*2 + PPB_ELEMS*4 + SCR_BYTES)

static char* g_fallback = nullptr;
__attribute__((constructor)) static void alloc_fallback() {
    (void)hipMalloc((void**)&g_fallback, TOTAL_BYTES);
}

// ---- async global->LDS (16B per lane; LDS dest = wave base + lane*16) -----
typedef __attribute__((address_space(3))) uint8_t* as3p;
typedef const __attribute__((address_space(1))) uint8_t* as1p;
__device__ __forceinline__ void gload_lds16(const void* g, void* l) {
    __builtin_amdgcn_global_load_lds((as1p)(const uint8_t*)g,
                                     (as3p)(uint32_t)(uintptr_t)l, 16, 0, 0);
}

__device__ __forceinline__ float bf2f(short s) {
    return __uint_as_float(((uint32_t)(uint16_t)s) << 16);
}
__device__ __forceinline__ short f2bf(float f) {
    return (short)__bfloat16_as_ushort(__float2bfloat16(f));
}

// ---------------------------------------------------------------------------
// weight convert fp32 -> bf16 (4 elems/thread)
// ---------------------------------------------------------------------------
__global__ __launch_bounds__(256) void cvt_kernel(
    const float* __restrict__ w, bf16* __restrict__ o, int n4)
{
    int i = blockIdx.x * 256 + threadIdx.x;
    if (i >= n4) return;
    float4 f = ((const float4*)w)[i];
    bf16* d = o + (size_t)i * 4;
    d[0] = __float2bfloat16(f.x);
    d[1] = __float2bfloat16(f.y);
    d[2] = __float2bfloat16(f.z);
    d[3] = __float2bfloat16(f.w);
}

// ---------------------------------------------------------------------------
// build_x: xb[n*32+w,:] = bf16(feats[b, max(t+w-31,0),:] + pos[w,:])
// ---------------------------------------------------------------------------
__global__ __launch_bounds__(256) void build_x_kernel(
    const float* __restrict__ feats,
    const float* __restrict__ pos,
    bf16* __restrict__ xb)
{
    int gid   = blockIdx.x * 256 + threadIdx.x;   // over NTOK * (D/4)
    int token = gid >> 7;
    int c4    = (gid & 127) * 4;
    int w     = token & (W_-1);
    int n     = token >> 5;
    int t     = n & (T_-1);
    int b     = n >> 8;
    int frame = t + w - (W_-1); if (frame < 0) frame = 0;
    const float4 f = *(const float4*)(feats + ((size_t)(b*T_ + frame)*D_ + c4));
    const float4 p = *(const float4*)(pos   + ((size_t)w*D_ + c4));
    bf16* d = xb + (size_t)token*D_ + c4;
    d[0] = __float2bfloat16(f.x + p.x);
    d[1] = __float2bfloat16(f.y + p.y);
    d[2] = __float2bfloat16(f.z + p.z);
    d[3] = __float2bfloat16(f.w + p.w);
}

// ---------------------------------------------------------------------------
// build_fb: factor matrix for layer-0 qkv.
// ---------------------------------------------------------------------------
__global__ __launch_bounds__(256) void build_fb_kernel(
    const float* __restrict__ feats,
    const float* __restrict__ pos,
    bf16* __restrict__ fb)
{
    int gid = blockIdx.x * 256 + threadIdx.x;     // over FROWS * (D/4)
    int row = gid >> 7;
    int c4  = (gid & 127) * 4;
    bf16* d = fb + (size_t)row * D_ + c4;
    float4 f;
    if (row < 2048)      f = *(const float4*)(feats + (size_t)row * D_ + c4);
    else if (row < 2080) f = *(const float4*)(pos + (size_t)(row - 2048) * D_ + c4);
    else                 f = make_float4(0.f, 0.f, 0.f, 0.f);
    d[0] = __float2bfloat16(f.x);
    d[1] = __float2bfloat16(f.y);
    d[2] = __float2bfloat16(f.z);
    d[3] = __float2bfloat16(f.w);
}

// ---------------------------------------------------------------------------
// build_ppb: ppb[w][c] = f32(qf[2048+w][c]) + bq[c]
// ---------------------------------------------------------------------------
__global__ __launch_bounds__(256) void build_ppb_kernel(
    const bf16* __restrict__ qf,
    const float* __restrict__ bq,
    float* __restrict__ ppb)
{
    int gid = blockIdx.x * 256 + threadIdx.x;   // over 32*1536
    int w = gid / (3*D_), c = gid % (3*D_);
    ppb[gid] = bf2f(*(const short*)(qf + (size_t)(2048 + w) * (3*D_) + c)) + bq[c];
}

// ---------------------------------------------------------------------------
// slice31: xg[n,:] = xb[n*32+31,:]
// ---------------------------------------------------------------------------
__global__ __launch_bounds__(256) void slice31_kernel(
    const bf16* __restrict__ xb, bf16* __restrict__ xg)
{
    int gid = blockIdx.x * 256 + threadIdx.x;   // over NWIN*64
    int n = gid >> 6, c0 = (gid & 63) * 8;
    *(bf16x8*)(xg + (size_t)n*D_ + c0) =
        *(const bf16x8*)(xb + (size_t)(n*W_ + (W_-1))*D_ + c0);
}

// ---------------------------------------------------------------------------
// 128x128 bf16 MFMA GEMM (32x32x16) — layer-0 factor GEMM, layer-3 smalls.
// ---------------------------------------------------------------------------
template<bool RELU, bool BIAS, bool REMAP>
__global__ __launch_bounds__(256) void gemm_bf16(
    const bf16* __restrict__ A,
    const bf16* __restrict__ Bt,
    const float* __restrict__ bias,
    bf16* __restrict__ Cb,
    int M, int N, int K)
{
    __shared__ bf16 As[128*32];
    __shared__ bf16 Bs[128*32];

    const int tid  = threadIdx.x;
    const int lane = tid & 63;
    const int wv   = tid >> 6;

    const int gridN = N >> 7;
    const int bid   = blockIdx.x;
    int m0, n0;
    if (REMAP) {
        const int q_ = bid >> 3;
        n0 = (q_ % gridN) << 7;
        m0 = (((q_ / gridN) * 8) + (bid & 7)) << 7;
    } else {
        n0 = (bid % gridN) << 7;
        m0 = (bid / gridN) << 7;
    }

    const int wm = (wv >> 1) * 64;
    const int wn = (wv & 1) * 64;

    f32x16 acc[2][2] = {};

    const int   srow  = wv*16 + (lane >> 2);
    const int   skoff = (lane & 3) * 8;
    const bf16* ga0 = A  + (size_t)(m0 + srow)      * K + skoff;
    const bf16* ga1 = A  + (size_t)(m0 + 64 + srow) * K + skoff;
    const bf16* gb0 = Bt + (size_t)(n0 + srow)      * K + skoff;
    const bf16* gb1 = Bt + (size_t)(n0 + 64 + srow) * K + skoff;
    char* lAs = (char*)As;
    char* lBs = (char*)Bs;
    const int l0 = wv*1024 + lane*16;

    const int r32  = lane & 31;
    const int ksel = (lane >> 5) * 16;

    for (int k0 = 0; k0 < K; k0 += 32) {
        gload_lds16(ga0 + k0, lAs + l0);
        gload_lds16(ga1 + k0, lAs + l0 + 4096);
        gload_lds16(gb0 + k0, lBs + l0);
        gload_lds16(gb1 + k0, lBs + l0 + 4096);
        __syncthreads();

        bf16x8 av[2][2], bv[2][2];
#pragma unroll
        for (int i = 0; i < 2; ++i)
#pragma unroll
            for (int h = 0; h < 2; ++h) {
                av[i][h] = *(const bf16x8*)(lAs + (wm + i*32 + r32)*64 + h*32 + ksel);
                bv[i][h] = *(const bf16x8*)(lBs + (wn + i*32 + r32)*64 + h*32 + ksel);
            }
#pragma unroll
        for (int i = 0; i < 2; ++i)
#pragma unroll
            for (int j = 0; j < 2; ++j) {
                acc[i][j] = __builtin_amdgcn_mfma_f32_32x32x16_bf16(
                    av[i][0], bv[j][0], acc[i][j], 0, 0, 0);
                acc[i][j] = __builtin_amdgcn_mfma_f32_32x32x16_bf16(
                    av[i][1], bv[j][1], acc[i][j], 0, 0, 0);
            }
        __syncthreads();
    }

    const int rbase = (lane >> 5) * 4;
#pragma unroll
    for (int i = 0; i < 2; ++i) {
#pragma unroll
        for (int j = 0; j < 2; ++j) {
            const int ncol = n0 + wn + j*32 + r32;
            const float bv_ = BIAS ? bias[ncol] : 0.f;
#pragma unroll
            for (int reg = 0; reg < 16; ++reg) {
                const int mrow = m0 + wm + i*32 + (reg & 3) + 8*(reg >> 2) + rbase;
                float v = acc[i][j][reg] + bv_;
                if (RELU) v = fmaxf(v, 0.f);
                Cb[(size_t)mrow * N + ncol] = __float2bfloat16(v);
            }
        }
    }
}

// ---------------------------------------------------------------------------
// 256x256 8-phase bf16 GEMM — r3-verified pipeline, panel-grouped XCD remap.
// Used for qkv (N=1536), W1 (N=2048), layer-3 kv (N=1024).
// Requires M%256==0, N%256==0, K%128==0, (M/256)%8==0.
// ---------------------------------------------------------------------------
template<bool RELU, bool BIAS>
__global__ __launch_bounds__(512, 2) void gemm256(
    const bf16* __restrict__ A,
    const bf16* __restrict__ Bt,
    const float* __restrict__ bias,
    bf16* __restrict__ Cb,
    int M, int N, int K)
{
    (void)M;
    __shared__ bf16 As[2][256*64];   // 32 KiB per buffer
    __shared__ bf16 Bs[2][256*64];

    const int tid  = threadIdx.x;
    const int lane = tid & 63;
    const int wv   = tid >> 6;       // 0..7
    const int wm   = wv >> 2;        // 0..1 : M-wave (128 rows)
    const int wn   = wv & 3;         // 0..3 : N-wave (64 cols)
    const int L    = lane & 15;
    const int qd   = lane >> 4;      // 0..3

    // panel-grouped XCD remap
    const int gridN = N >> 8;
    const int W8  = gridN << 3;
    const int bid = blockIdx.x;
    const int q_  = bid / W8;
    const int r_  = bid % W8;
    const int n0  = (r_ >> 3) << 8;
    const int m0  = ((q_ << 3) + (r_ & 7)) << 8;

    const int srow = tid >> 3;
    const int scol = ((tid & 7) ^ (srow & 7)) * 8;   // elements
    const bf16* gA = A  + (size_t)(m0 + srow) * K + scol;
    const bf16* gB = Bt + (size_t)(n0 + srow) * K + scol;
    const size_t rstep = (size_t)64 * K;             // +64 rows
    bf16* lA = &As[0][0] + tid * 8;
    bf16* lB = &Bs[0][0] + tid * 8;

    const int physk0 = ((qd)     ^ (L & 7)) * 8;     // kk=0 chunk
    const int physk1 = ((4 + qd) ^ (L & 7)) * 8;     // kk=1 chunk
    const int aoff = (wm*128 + L) * 64;
    const int boff = (wn*64  + L) * 64;

    f32x4 acc[8][4] = {};
    bf16x8 av0[4][2], av1[4][2], bv0[2][2], bv1[2][2];

#define STAGE_A2(b, kt) do { \
    const bf16* s_ = gA + (size_t)(kt) * 64; \
    bf16* d_ = lA + (b) * 16384; \
    gload_lds16(s_,            d_); \
    gload_lds16(s_ +   rstep,  d_ + 4096); \
    gload_lds16(s_ + 2*rstep,  d_ + 8192); \
    gload_lds16(s_ + 3*rstep,  d_ + 12288); } while (0)

#define STAGE_B2(b, kt) do { \
    const bf16* s_ = gB + (size_t)(kt) * 64; \
    bf16* d_ = lB + (b) * 16384; \
    gload_lds16(s_,            d_); \
    gload_lds16(s_ +   rstep,  d_ + 4096); \
    gload_lds16(s_ + 2*rstep,  d_ + 8192); \
    gload_lds16(s_ + 3*rstep,  d_ + 12288); } while (0)

#define LDA_(dst, b, qm) do { \
    const bf16* pa_ = &As[b][aoff + (qm)*4096]; \
    _Pragma("unroll") \
    for (int mr_ = 0; mr_ < 4; ++mr_) { \
        dst[mr_][0] = *(const bf16x8*)(pa_ + mr_*1024 + physk0); \
        dst[mr_][1] = *(const bf16x8*)(pa_ + mr_*1024 + physk1); } } while (0)

#define LDB_(dst, b, qn) do { \
    const bf16* pb_ = &Bs[b][boff + (qn)*2048]; \
    _Pragma("unroll") \
    for (int nr_ = 0; nr_ < 2; ++nr_) { \
        dst[nr_][0] = *(const bf16x8*)(pb_ + nr_*1024 + physk0); \
        dst[nr_][1] = *(const bf16x8*)(pb_ + nr_*1024 + physk1); } } while (0)

#define MMA_(qm, qn, av, bv) do { \
    _Pragma("unroll") \
    for (int mr_ = 0; mr_ < 4; ++mr_) \
    _Pragma("unroll") \
    for (int nr_ = 0; nr_ < 2; ++nr_) { \
        f32x4 c_ = acc[(qm)*4+mr_][(qn)*2+nr_]; \
        c_ = __builtin_amdgcn_mfma_f32_16x16x32_bf16(av[mr_][0], bv[nr_][0], c_, 0, 0, 0); \
        c_ = __builtin_amdgcn_mfma_f32_16x16x32_bf16(av[mr_][1], bv[nr_][1], c_, 0, 0, 0); \
        acc[(qm)*4+mr_][(qn)*2+nr_] = c_; } } while (0)

#define BAR_ __builtin_amdgcn_s_barrier()
#define LGKM0_ do { asm volatile("s_waitcnt lgkmcnt(0)" ::: "memory"); \
                    __builtin_amdgcn_sched_barrier(0); } while (0)

#define TILE_(b, kt2) do { \
    /* P1 */ \
    LDA_(av0, b, 0); LDB_(bv0, b, 0); \
    BAR_; LGKM0_; \
    __builtin_amdgcn_s_setprio(1); MMA_(0, 0, av0, bv0); __builtin_amdgcn_s_setprio(0); \
    BAR_; \
    /* P2 */ \
    LDB_(bv1, b, 1); \
    BAR_; LGKM0_; \
    __builtin_amdgcn_s_setprio(1); MMA_(0, 1, av0, bv1); __builtin_amdgcn_s_setprio(0); \
    BAR_; \
    /* P3 */ \
    LDA_(av1, b, 1); \
    STAGE_B2(b, kt2); \
    BAR_; LGKM0_; \
    __builtin_amdgcn_s_setprio(1); MMA_(1, 1, av1, bv1); __builtin_amdgcn_s_setprio(0); \
    BAR_; \
    /* P4 */ \
    STAGE_A2(b, kt2); \
    __builtin_amdgcn_s_setprio(1); MMA_(1, 0, av1, bv0); __builtin_amdgcn_s_setprio(0); \
    asm volatile("s_waitcnt vmcnt(8)" ::: "memory"); \
    BAR_; } while (0)

    const int nkt = K >> 6;

    STAGE_B2(0, 0); STAGE_A2(0, 0);
    STAGE_B2(1, 1); STAGE_A2(1, 1);
    asm volatile("s_waitcnt vmcnt(8)" ::: "memory");
    BAR_;

    for (int u = 0; u < nkt; u += 2) {
        int k2 = u + 2; if (k2 >= nkt) k2 -= nkt;
        int k3 = u + 3; if (k3 >= nkt) k3 -= nkt;
        TILE_(0, k2);
        TILE_(1, k3);
    }

    asm volatile("s_waitcnt vmcnt(0)" ::: "memory");

#pragma unroll
    for (int mr = 0; mr < 8; ++mr) {
        const int row = m0 + wm*128 + mr*16 + qd*4;
#pragma unroll
        for (int nr = 0; nr < 4; ++nr) {
            const int col = n0 + wn*64 + nr*16 + L;
            const float bb = BIAS ? bias[col] : 0.f;
            bf16* cp = Cb + (size_t)row * N + col;
#pragma unroll
            for (int rg = 0; rg < 4; ++rg) {
                float v = acc[mr][nr][rg] + bb;
                if (RELU) v = fmaxf(v, 0.f);
                cp[(size_t)rg * N] = __float2bfloat16(v);
            }
        }
    }

#undef STAGE_A2
#undef STAGE_B2
#undef LDA_
#undef LDB_
#undef MMA_
#undef BAR_
#undef LGKM0_
#undef TILE_
}

// ---------------------------------------------------------------------------
// gemmln: FUSED  xb = LN( A @ Bt^T + bias + xb ) * g + b   (N = 512 fixed)
// Tile 128x512 (full LN-row per block -> in-place xb update is safe),
// 512 thr / 8 waves (2M x 4N, wave 64x128, acc[4][8]); BK=32, triple-buffered
// LDS (120 KB), stage 2 tiles ahead, counted vmcnt(5) (never drains in-loop).
// Swizzle: r5's HW-verified 4-chunk XOR (phys = qd ^ ((row>>1)&3)).
// Epilogue: s = acc + bias + xb (f32); 16-lane shfl row-partials ->
// 4 KB LDS cross-wave (4 wn) reduce -> normalize -> scattered bf16 write.
// Race audit: stage target buf = tile t-1's, last read before t-1's BAR;
// vmcnt(0)+BAR before LDS scratch reuse; uniform control flow.
// ---------------------------------------------------------------------------
__global__ __launch_bounds__(512, 2) void gemmln(
    const bf16* __restrict__ A,     // (M, K)
    const bf16* __restrict__ Bt,    // (512, K)
    const float* __restrict__ bias, // (512)  y-bias
    bf16* __restrict__ xb,          // (M, 512) residual in/out
    const float* __restrict__ g,
    const float* __restrict__ b,
    int K)
{
    __shared__ bf16 As[3*128*32];   // 24 KB
    __shared__ bf16 Bs[3*512*32];   // 96 KB

    const int tid  = threadIdx.x;
    const int lane = tid & 63;
    const int wv   = tid >> 6;       // 0..7
    const int wm   = wv >> 2;        // 0..1 : M-wave (64 rows)
    const int wn   = wv & 3;         // 0..3 : N-wave (128 cols)
    const int L    = lane & 15;
    const int qd   = lane >> 4;      // 0..3

    const int m0 = blockIdx.x << 7;  // 128-row panel

    // staging: row = tid>>2 , phys chunk = tid&3; source pre-swizzled.
    const int srow = tid >> 2;                       // 0..127
    const int slog = (tid & 3) ^ ((srow >> 1) & 3);
    const bf16* gA = A  + (size_t)(m0 + srow) * K + slog * 8;
    const bf16* gB = Bt + (size_t)srow * K + slog * 8;
    const size_t rb = (size_t)128 * K;               // +128 B-rows
    bf16* lA = As + tid * 8;
    bf16* lB = Bs + tid * 8;

    const int kch  = (qd ^ ((L >> 1) & 3)) * 8;
    const int aoff = (wm*64  + L) * 32 + kch;        // + mr*512
    const int boff = (wn*128 + L) * 32 + kch;        // + nr*512

    f32x4 acc[4][8] = {};

#define STG_(buf, kt) do { \
    gload_lds16(gA + (size_t)(kt) * 32, lA + (buf) * 4096); \
    const bf16* s_ = gB + (size_t)(kt) * 32; \
    bf16* d_ = lB + (buf) * 16384; \
    gload_lds16(s_,         d_); \
    gload_lds16(s_ +   rb,  d_ + 4096); \
    gload_lds16(s_ + 2*rb,  d_ + 8192); \
    gload_lds16(s_ + 3*rb,  d_ + 12288); } while (0)

#define BAR_ __builtin_amdgcn_s_barrier()

    const int nt = K >> 5;           // 16 (K=512) or 64 (K=2048)

    STG_(0, 0);
    STG_(1, 1);
    asm volatile("s_waitcnt vmcnt(5)" ::: "memory");
    BAR_;

    int b0 = 0;
    for (int t = 0; t < nt; ++t) {
        const int tgt = (b0 + 2 >= 3) ? b0 - 1 : b0 + 2;
        const int kt2 = (t + 2 < nt) ? t + 2 : t;   // tail re-stage: never read
        STG_(tgt, kt2);

        bf16x8 av[4], bv[8];
        const bf16* pa = As + b0*4096  + aoff;
        const bf16* pb = Bs + b0*16384 + boff;
#pragma unroll
        for (int mr = 0; mr < 4; ++mr) av[mr] = *(const bf16x8*)(pa + mr*512);
#pragma unroll
        for (int nr = 0; nr < 8; ++nr) bv[nr] = *(const bf16x8*)(pb + nr*512);
        asm volatile("s_waitcnt lgkmcnt(0)" ::: "memory");
        __builtin_amdgcn_sched_barrier(0);
        __builtin_amdgcn_s_setprio(1);
#pragma unroll
        for (int mr = 0; mr < 4; ++mr)
#pragma unroll
            for (int nr = 0; nr < 8; ++nr)
                acc[mr][nr] = __builtin_amdgcn_mfma_f32_16x16x32_bf16(
                    av[mr], bv[nr], acc[mr][nr], 0, 0, 0);
        __builtin_amdgcn_s_setprio(0);
        asm volatile("s_waitcnt vmcnt(5)" ::: "memory");
        BAR_;
        b0 = (b0 == 2) ? 0 : b0 + 1;
    }

    // drain all pending LDS-targeted loads, then reuse As as LN scratch
    asm volatile("s_waitcnt vmcnt(0)" ::: "memory");
    BAR_;

    float* lnred = (float*)As;       // [4 wn][128 rows][2] = 4 KB

    // hoist per-col constants (8 cols per thread)
    float bias8[8], gg8[8], bb8[8];
#pragma unroll
    for (int nr = 0; nr < 8; ++nr) {
        const int col = wn*128 + nr*16 + L;
        bias8[nr] = bias[col];
        gg8[nr]   = g[col];
        bb8[nr]   = b[col];
    }

    // s = acc + bias + xb ; per-row partial sums -> LDS
#pragma unroll
    for (int mr = 0; mr < 4; ++mr) {
#pragma unroll
        for (int rg = 0; rg < 4; ++rg) {
            const int row = wm*64 + mr*16 + qd*4 + rg;   // 0..127
            const bf16* xr = xb + (size_t)(m0 + row) * D_ + wn*128 + L;
            float ps = 0.f, pq = 0.f;
#pragma unroll
            for (int nr = 0; nr < 8; ++nr) {
                float s = acc[mr][nr][rg] + bias8[nr]
                        + bf2f(*(const short*)(xr + nr*16));
                acc[mr][nr][rg] = s;
                ps += s; pq += s*s;
            }
#pragma unroll
            for (int m = 1; m < 16; m <<= 1) {
                ps += __shfl_xor(ps, m);
                pq += __shfl_xor(pq, m);
            }
            if (L == 0) {
                lnred[(wn*128 + row)*2    ] = ps;
                lnred[(wn*128 + row)*2 + 1] = pq;
            }
        }
    }
    BAR_;

    // normalize + write
#pragma unroll
    for (int mr = 0; mr < 4; ++mr) {
#pragma unroll
        for (int rg = 0; rg < 4; ++rg) {
            const int row = wm*64 + mr*16 + qd*4 + rg;
            float S = 0.f, Q = 0.f;
#pragma unroll
            for (int w4 = 0; w4 < 4; ++w4) {
                S += lnred[(w4*128 + row)*2    ];
                Q += lnred[(w4*128 + row)*2 + 1];
            }
            const float mu = S * (1.f / D_);
            float var = Q * (1.f / D_) - mu * mu;
            if (var < 0.f) var = 0.f;
            const float rs = rsqrtf(var + 1e-5f);
            bf16* xw = xb + (size_t)(m0 + row) * D_ + wn*128 + L;
#pragma unroll
            for (int nr = 0; nr < 8; ++nr) {
                float o = (acc[mr][nr][rg] - mu) * rs * gg8[nr] + bb8[nr];
                *(short*)(xw + nr*16) = f2bf(o);
            }
        }
    }

#undef STG_
#undef BAR_
}

// ---------------------------------------------------------------------------
// Fused residual-add + LayerNorm (layer-3 small path only)
// ---------------------------------------------------------------------------
__global__ __launch_bounds__(256) void lnres_kernel(
    const bf16* __restrict__ y,
    const bf16* __restrict__ xin,
    bf16* __restrict__ xout,
    const float* __restrict__ g,
    const float* __restrict__ b,
    int xin_stride)
{
    const int wave  = threadIdx.x >> 6;
    const int lane  = threadIdx.x & 63;
    const int token = blockIdx.x * 4 + wave;
    const int c0    = lane * 8;

    const bf16* yr = y    + (size_t)token * D_ + c0;
    const bf16* xr = xin  + (size_t)token * xin_stride + c0;
    bf16*       xo = xout + (size_t)token * D_ + c0;

    bf16x8 ty = *(const bf16x8*)yr;
    bf16x8 tx = *(const bf16x8*)xr;

    float v[8];
    float s1 = 0.f, s2 = 0.f;
#pragma unroll
    for (int j = 0; j < 8; ++j) {
        v[j] = bf2f(ty[j]) + bf2f(tx[j]);
        s1 += v[j]; s2 += v[j]*v[j];
    }
#pragma unroll
    for (int mask = 1; mask < 64; mask <<= 1) {
        s1 += __shfl_xor(s1, mask);
        s2 += __shfl_xor(s2, mask);
    }
    const float mu = s1 * (1.f / D_);
    float var = s2 * (1.f / D_) - mu * mu;
    if (var < 0.f) var = 0.f;
    const float rs = rsqrtf(var + 1e-5f);

    const float4 g0 = *(const float4*)(g + c0);
    const float4 g1 = *(const float4*)(g + c0 + 4);
    const float4 b0 = *(const float4*)(b + c0);
    const float4 b1 = *(const float4*)(b + c0 + 4);
    const float gg[8] = {g0.x,g0.y,g0.z,g0.w,g1.x,g1.y,g1.z,g1.w};
    const float bb[8] = {b0.x,b0.y,b0.z,b0.w,b1.x,b1.y,b1.z,b1.w};

    bf16x8 o;
#pragma unroll
    for (int j = 0; j < 8; ++j) {
        float t = (v[j] - mu) * rs * gg[j] + bb[j];
        o[j] = f2bf(t);
    }
    *(bf16x8*)xo = o;
}

// ---------------------------------------------------------------------------
// MFMA attention — one WAVE per (window, head). W=32, dh=64. (layers 1..2)
// ---------------------------------------------------------------------------
__global__ __launch_bounds__(256) void attn_mfma(
    const bf16* __restrict__ qkv,   // (NTOK, 1536)
    bf16* __restrict__ ctx)         // (NTOK, 512)
{
    __shared__ short Pb[4][32*32];

    const int tid  = threadIdx.x;
    const int lane = tid & 63;
    const int wv   = tid >> 6;
    const int pair = blockIdx.x * 4 + wv;
    const int win  = pair >> 3;
    const int h    = pair & 7;

    const int quad = lane >> 4;
    const int col  = lane & 15;

    const bf16* base = qkv + (size_t)win * W_ * (3*D_) + h * DH_;

    bf16x8 bvv[4];
    {
        const short* vbase = (const short*)(base + 2*D_);
#pragma unroll
        for (int ntd = 0; ntd < 4; ++ntd)
#pragma unroll
            for (int jj = 0; jj < 8; ++jj)
                bvv[ntd][jj] = vbase[(size_t)(quad*8 + jj) * (3*D_) + ntd*16 + col];
    }

    bf16x8 aq[2][2], bk[2][2];
#pragma unroll
    for (int mt = 0; mt < 2; ++mt)
#pragma unroll
        for (int kq = 0; kq < 2; ++kq)
            aq[mt][kq] = *(const bf16x8*)(base + (size_t)(mt*16 + col) * (3*D_)
                                          + kq*32 + quad*8);
#pragma unroll
    for (int nt = 0; nt < 2; ++nt)
#pragma unroll
        for (int kq = 0; kq < 2; ++kq)
            bk[nt][kq] = *(const bf16x8*)(base + D_ + (size_t)(nt*16 + col) * (3*D_)
                                          + kq*32 + quad*8);

    f32x4 S[2][2] = {};
#pragma unroll
    for (int mt = 0; mt < 2; ++mt)
#pragma unroll
        for (int nt = 0; nt < 2; ++nt) {
            S[mt][nt] = __builtin_amdgcn_mfma_f32_16x16x32_bf16(
                aq[mt][0], bk[nt][0], S[mt][nt], 0, 0, 0);
            S[mt][nt] = __builtin_amdgcn_mfma_f32_16x16x32_bf16(
                aq[mt][1], bk[nt][1], S[mt][nt], 0, 0, 0);
        }

    short* P = Pb[wv];
#pragma unroll
    for (int mt = 0; mt < 2; ++mt) {
#pragma unroll
        for (int reg = 0; reg < 4; ++reg) {
            const int row = mt*16 + quad*4 + reg;
            float v0 = (col      <= row) ? S[mt][0][reg] * 0.125f : -1e30f;
            float v1 = (16 + col <= row) ? S[mt][1][reg] * 0.125f : -1e30f;
            float mx = fmaxf(v0, v1);
#pragma unroll
            for (int m = 1; m < 16; m <<= 1) mx = fmaxf(mx, __shfl_xor(mx, m));
            float e0 = __expf(v0 - mx);
            float e1 = __expf(v1 - mx);
            float sm = e0 + e1;
#pragma unroll
            for (int m = 1; m < 16; m <<= 1) sm += __shfl_xor(sm, m);
            float inv = 1.f / sm;
            P[row*32 + col]      = f2bf(e0 * inv);
            P[row*32 + 16 + col] = f2bf(e1 * inv);
        }
    }

    bf16* cb = ctx + (size_t)win * W_ * D_ + h * DH_;
#pragma unroll
    for (int mt = 0; mt < 2; ++mt) {
        bf16x8 ap = *(const bf16x8*)(P + (mt*16 + col)*32 + quad*8);
#pragma unroll
        for (int ntd = 0; ntd < 4; ++ntd) {
            f32x4 O = {};
            O = __builtin_amdgcn_mfma_f32_16x16x32_bf16(ap, bvv[ntd], O, 0, 0, 0);
#pragma unroll
            for (int reg = 0; reg < 4; ++reg) {
                const int row = mt*16 + quad*4 + reg;
                cb[(size_t)row * D_ + ntd*16 + col] = __float2bfloat16(O[reg]);
            }
        }
    }
}

// ---------------------------------------------------------------------------
// attn_mfma0: layer-0 attention straight from the factor matrix.
// ---------------------------------------------------------------------------
__global__ __launch_bounds__(256) void attn_mfma0(
    const bf16* __restrict__ qf,    // (FROWS, 1536)
    const float* __restrict__ ppb,  // (32, 1536)
    bf16* __restrict__ ctx)         // (NTOK, 512)
{
    __shared__ short Pb[4][32*32];

    const int tid  = threadIdx.x;
    const int lane = tid & 63;
    const int wv   = tid >> 6;
    const int pair = blockIdx.x * 4 + wv;
    const int win  = pair >> 3;
    const int h    = pair & 7;

    const int quad = lane >> 4;
    const int col  = lane & 15;
    const int bb_  = win >> 8;
    const int tt_  = win & (T_-1);

#define FR_(w) ((size_t)(bb_*T_ + ((tt_ + (w) - (W_-1)) > 0 ? (tt_ + (w) - (W_-1)) : 0)) * (3*D_))

    bf16x8 bvv[4];
#pragma unroll
    for (int ntd = 0; ntd < 4; ++ntd)
#pragma unroll
        for (int jj = 0; jj < 8; ++jj) {
            const int w2 = quad*8 + jj;
            const int c  = 2*D_ + h*DH_ + ntd*16 + col;
            bvv[ntd][jj] = f2bf(bf2f(*(const short*)(qf + FR_(w2) + c))
                                + ppb[w2*(3*D_) + c]);
        }

    bf16x8 aq[2][2], bk[2][2];
#pragma unroll
    for (int mt = 0; mt < 2; ++mt)
#pragma unroll
        for (int kq = 0; kq < 2; ++kq) {
            const int w  = mt*16 + col;
            const size_t fro = FR_(w);
            const int cq = h*DH_ + kq*32 + quad*8;
            const bf16x8 a = *(const bf16x8*)(qf + fro + cq);
            const bf16x8 k = *(const bf16x8*)(qf + fro + D_ + cq);
            const float* pq = ppb + w*(3*D_) + cq;
            const float* pk = pq + D_;
#pragma unroll
            for (int j = 0; j < 8; ++j) {
                aq[mt][kq][j] = f2bf(bf2f(a[j]) + pq[j]);
                bk[mt][kq][j] = f2bf(bf2f(k[j]) + pk[j]);
            }
        }
#undef FR_

    f32x4 S[2][2] = {};
#pragma unroll
    for (int mt = 0; mt < 2; ++mt)
#pragma unroll
        for (int nt = 0; nt < 2; ++nt) {
            S[mt][nt] = __builtin_amdgcn_mfma_f32_16x16x32_bf16(
                aq[mt][0], bk[nt][0], S[mt][nt], 0, 0, 0);
            S[mt][nt] = __builtin_amdgcn_mfma_f32_16x16x32_bf16(
                aq[mt][1], bk[nt][1], S[mt][nt], 0, 0, 0);
        }

    short* P = Pb[wv];
#pragma unroll
    for (int mt = 0; mt < 2; ++mt) {
#pragma unroll
        for (int reg = 0; reg < 4; ++reg) {
            const int row = mt*16 + quad*4 + reg;
            float v0 = (col      <= row) ? S[mt][0][reg] * 0.125f : -1e30f;
            float v1 = (16 + col <= row) ? S[mt][1][reg] * 0.125f : -1e30f;
            float mx = fmaxf(v0, v1);
#pragma unroll
            for (int m = 1; m < 16; m <<= 1) mx = fmaxf(mx, __shfl_xor(mx, m));
            float e0 = __expf(v0 - mx);
            float e1 = __expf(v1 - mx);
            float sm = e0 + e1;
#pragma unroll
            for (int m = 1; m < 16; m <<= 1) sm += __shfl_xor(sm, m);
            float inv = 1.f / sm;
            P[row*32 + col]      = f2bf(e0 * inv);
            P[row*32 + 16 + col] = f2bf(e1 * inv);
        }
    }

    bf16* cb = ctx + (size_t)win * W_ * D_ + h * DH_;
#pragma unroll
    for (int mt = 0; mt < 2; ++mt) {
        bf16x8 ap = *(const bf16x8*)(P + (mt*16 + col)*32 + quad*8);
#pragma unroll
        for (int ntd = 0; ntd < 4; ++ntd) {
            f32x4 O = {};
            O = __builtin_amdgcn_mfma_f32_16x16x32_bf16(ap, bvv[ntd], O, 0, 0, 0);
#pragma unroll
            for (int reg = 0; reg < 4; ++reg) {
                const int row = mt*16 + quad*4 + reg;
                cb[(size_t)row * D_ + ntd*16 + col] = __float2bfloat16(O[reg]);
            }
        }
    }
}

// ---------------------------------------------------------------------------
// attn_last2: layer-3 attention, queries at w=31 only, split K/V input.
// ---------------------------------------------------------------------------
__global__ __launch_bounds__(256) void attn_last2(
    const bf16* __restrict__ kv,    // (NTOK, 1024) = [K|V]
    const bf16* __restrict__ q31,   // (NWIN, 512)
    bf16* __restrict__ ctxl)        // (NWIN, 512)
{
    __shared__ float Ps[4][32];

    const int wv   = threadIdx.x >> 6;
    const int lane = threadIdx.x & 63;
    const int pair = blockIdx.x * 4 + wv;
    const int win  = pair >> 3;
    const int h    = pair & 7;

    const bf16* kb   = kv + (size_t)win * W_ * 1024 + h * DH_;
    const short* qrow = (const short*)(q31 + (size_t)win * D_ + h * DH_);

    const int k    = lane & 31;
    const int half = lane >> 5;
    const short* krow = (const short*)(kb + (size_t)k * 1024 + half*32);

    float s = 0.f;
    const bf16x8* q8 = (const bf16x8*)(qrow + half*32);
    const bf16x8* k8 = (const bf16x8*)krow;
#pragma unroll
    for (int c = 0; c < 4; ++c) {
        bf16x8 qa = q8[c], kb_ = k8[c];
#pragma unroll
        for (int j = 0; j < 8; ++j) s += bf2f(qa[j]) * bf2f(kb_[j]);
    }
    s += __shfl_xor(s, 32);
    s *= 0.125f;

    float mx = s;
#pragma unroll
    for (int m = 1; m < 32; m <<= 1) mx = fmaxf(mx, __shfl_xor(mx, m));
    float e = __expf(s - mx);
    float sum = e;
#pragma unroll
    for (int m = 1; m < 32; m <<= 1) sum += __shfl_xor(sum, m);
    if (half == 0) Ps[wv][k] = e / sum;
    __syncthreads();

    const short* vb = (const short*)(kb + 512);
    float o = 0.f;
#pragma unroll
    for (int kk = 0; kk < 32; ++kk)
        o += Ps[wv][kk] * bf2f(vb[(size_t)kk * 1024 + lane]);

    ctxl[(size_t)win * D_ + h * DH_ + lane] = __float2bfloat16(o);
}

// ---------------------------------------------------------------------------
// Head: token = xq[n,:] bf16; logits (NWIN,6) then values (NWIN)
// ---------------------------------------------------------------------------
__global__ __launch_bounds__(64) void head_kernel(
    const bf16* __restrict__ xq,
    const float* __restrict__ Wp, const float* __restrict__ bp,
    const float* __restrict__ Wv, const float* __restrict__ bv,
    float* __restrict__ out)
{
    const int n    = blockIdx.x;
    const int lane = threadIdx.x;
    const bf16* row = xq + (size_t)n * D_;
    float t[8];
#pragma unroll
    for (int j = 0; j < 8; ++j) t[j] = bf2f(*(const short*)(row + lane + j*64));

    for (int a = 0; a < A_ + 1; ++a) {
        const float* w = (a < A_) ? (Wp + (size_t)a * D_) : Wv;
        float d = 0.f;
#pragma unroll
        for (int j = 0; j < 8; ++j) d += t[j] * w[lane + j*64];
#pragma unroll
        for (int off = 32; off > 0; off >>= 1) d += __shfl_down(d, off);
        if (lane == 0) {
            if (a < A_) out[(size_t)n*A_ + a] = d + bp[a];
            else        out[(size_t)NWIN*A_ + n] = d + bv[0];
        }
    }
}

// ---------------------------------------------------------------------------
extern "C" void kernel_launch(void* const* d_in, const int* in_sizes, int n_in,
                              void* d_out, int out_size, void* d_ws, size_t ws_size,
                              hipStream_t stream) {
    const float* feats = (const float*)d_in[0];
    const float* pos   = (const float*)d_in[1];
    const float* Wqkv  = (const float*)d_in[2];
    const float* bqkv  = (const float*)d_in[3];
    const float* Wo    = (const float*)d_in[4];
    const float* bo    = (const float*)d_in[5];
    const float* ln1g  = (const float*)d_in[6];
    const float* ln1b  = (const float*)d_in[7];
    const float* W1    = (const float*)d_in[8];
    const float* b1    = (const float*)d_in[9];
    const float* W2    = (const float*)d_in[10];
    const float* b2    = (const float*)d_in[11];
    const float* ln2g  = (const float*)d_in[12];
    const float* ln2b  = (const float*)d_in[13];
    const float* Wp    = (const float*)d_in[14];
    const float* bp    = (const float*)d_in[15];
    const float* Wv    = (const float*)d_in[16];
    const float* bv    = (const float*)d_in[17];
    float* out = (float*)d_out;

    char* basep = (ws_size >= TOTAL_BYTES) ? (char*)d_ws : g_fallback;

    bf16*  xb   = (bf16*)basep;
    bf16*  wq_b = (bf16*)(basep + XB_BYTES);
    bf16*  wo_b = wq_b + WQ_ELEMS;
    bf16*  w1_b = wo_b + WO_ELEMS;
    bf16*  w2_b = w1_b + W1_ELEMS;
    bf16*  fb   = w2_b + W2_ELEMS;                 // (FROWS, 512)
    bf16*  qf   = fb + FB_ELEMS;                   // (FROWS, 1536)
    float* ppb  = (float*)(qf + QF_ELEMS);         // (32, 1536) fp32
    bf16*  scr  = (bf16*)(ppb + PPB_ELEMS);
    bf16*  qkv_s = scr;                            // (NTOK, 1536) attn phase
    bf16*  kv_s  = scr;                            // (NTOK, 1024) layer-3
    bf16*  ctx_s = scr + (size_t)NTOK * (3*D_);    // (NTOK, 512)  attn phase
    bf16*  h_s   = scr;                            // (NTOK, 2048) FFN phase
    // layer-3 compact buffers, carved from ctx_s region
    bf16*  ctxl = ctx_s;                           // (NWIN, 512)
    bf16*  ysm  = ctx_s + (size_t)SMALL;           // (NWIN, 512)
    bf16*  hsm  = ctx_s + (size_t)2*SMALL;         // (NWIN, 2048)
    bf16*  xq   = ctx_s + (size_t)6*SMALL;         // (NWIN, 512)
    bf16*  xg   = ctx_s + (size_t)8*SMALL;         // (NWIN, 512) xb rows w=31
    bf16*  q31  = ctx_s + (size_t)9*SMALL;         // (NWIN, 512)

    cvt_kernel<<<(WQ_ELEMS/4 + 255)/256, 256, 0, stream>>>(Wqkv, wq_b, WQ_ELEMS/4);
    cvt_kernel<<<(WO_ELEMS/4 + 255)/256, 256, 0, stream>>>(Wo,   wo_b, WO_ELEMS/4);
    cvt_kernel<<<(W1_ELEMS/4 + 255)/256, 256, 0, stream>>>(W1,   w1_b, W1_ELEMS/4);
    cvt_kernel<<<(W2_ELEMS/4 + 255)/256, 256, 0, stream>>>(W2,   w2_b, W2_ELEMS/4);

    build_x_kernel<<<NTOK * (D_/4) / 256, 256, 0, stream>>>(feats, pos, xb);
    build_fb_kernel<<<FROWS * (D_/4) / 256, 256, 0, stream>>>(feats, pos, fb);

    const int GM2 = NTOK / 256;   // 256 m-panels (%8==0, remap ok)
    const int GL  = NTOK / 128;   // 512 blocks for gemmln

    for (int i = 0; i < L_; ++i) {
        const bf16*  wq_i = wq_b + (size_t)i * 3*D_*D_;
        const float* bq_i = bqkv + (size_t)i * 3*D_;
        const bf16*  wo_i = wo_b + (size_t)i * D_*D_;
        const float* bo_i = bo   + (size_t)i * D_;
        const bf16*  w1_i = w1_b + (size_t)i * 4*D_*D_;
        const float* b1_i = b1   + (size_t)i * 4*D_;
        const bf16*  w2_i = w2_b + (size_t)i * 4*D_*D_;
        const float* b2_i = b2   + (size_t)i * D_;

        if (i == 0) {
            // layer-0 qkv via factors; attention reads qf directly.
            gemm_bf16<false,false,false><<<(FROWS/128) * (3*D_/128), 256, 0, stream>>>(
                fb, wq_i, nullptr, qf, FROWS, 3*D_, D_);
            build_ppb_kernel<<<W_*(3*D_)/256, 256, 0, stream>>>(qf, bq_i, ppb);
            attn_mfma0<<<NWIN * H_ / 4, 256, 0, stream>>>(qf, ppb, ctx_s);
        } else if (i < L_-1) {
            // qkv = xb @ Wqkv^T + bq : N=1536, K=512
            gemm256<false,true><<<GM2 * (3*D_/256), 512, 0, stream>>>(
                xb, wq_i, bq_i, qkv_s, NTOK, 3*D_, D_);
            attn_mfma<<<NWIN * H_ / 4, 256, 0, stream>>>(qkv_s, ctx_s);
        }

        if (i < L_-1) {
            // xb = LN1(ctx @ Wo^T + bo + xb)  [fused]
            gemmln<<<GL, 512, 0, stream>>>(
                ctx_s, wo_i, bo_i, xb,
                ln1g + (size_t)i*D_, ln1b + (size_t)i*D_, D_);
            // h = relu(xb @ W1^T + b1) : N=2048, K=512
            gemm256<true,true><<<GM2 * (4*D_/256), 512, 0, stream>>>(
                xb, w1_i, b1_i, h_s, NTOK, 4*D_, D_);
            // xb = LN2(h @ W2^T + b2 + xb)  [fused, K=2048]
            gemmln<<<GL, 512, 0, stream>>>(
                h_s, w2_i, b2_i, xb,
                ln2g + (size_t)i*D_, ln2b + (size_t)i*D_, 4*D_);
        } else {
            // last layer: K/V for all tokens (N=1024), Q only at w=31.
            gemm256<false,true><<<GM2 * (1024/256), 512, 0, stream>>>(
                xb, wq_i + (size_t)D_*D_, bq_i + D_, kv_s, NTOK, 2*D_, D_);
            slice31_kernel<<<NWIN*64/256, 256, 0, stream>>>(xb, xg);
            gemm_bf16<false,true,false><<<(NWIN/128) * (D_/128), 256, 0, stream>>>(
                xg, wq_i, bq_i, q31, NWIN, D_, D_);
            attn_last2<<<NWIN * H_ / 4, 256, 0, stream>>>(kv_s, q31, ctxl);
            gemm_bf16<false,true,false><<<(NWIN/128) * (D_/128), 256, 0, stream>>>(
                ctxl, wo_i, bo_i, ysm, NWIN, D_, D_);
            lnres_kernel<<<NWIN/4, 256, 0, stream>>>(
                ysm, xg, xq,
                ln1g + (size_t)i*D_, ln1b + (size_t)i*D_, D_);
            gemm_bf16<true,true,false><<<(NWIN/128) * (4*D_/128), 256, 0, stream>>>(
                xq, w1_i, b1_i, hsm, NWIN, 4*D_, D_);
            gemm_bf16<false,true,false><<<(NWIN/128) * (D_/128), 256, 0, stream>>>(
                hsm, w2_i, b2_i, ysm, NWIN, D_, 4*D_);
            lnres_kernel<<<NWIN/4, 256, 0, stream>>>(
                ysm, xq, xq, ln2g + (size_t)i*D_, ln2b + (size_t)i*D_, D_);
        }
    }

    head_kernel<<<NWIN, 64, 0, stream>>>(xq, Wp, bp, Wv, bv, out);
}

// Round 8
// 1998.548 us; speedup vs baseline: 1.1187x; 1.1187x over previous
//
#include <hip/hip_runtime.h>
#include <hip/hip_bf16.h>
#include <cstdint>
#include <cstddef>

// Problem constants (fixed by reference)
#define B_    8
#define T_    256
#define D_    512
#define W_    32
#define L_    4
#define A_    6
#define H_    8
#define DH_   64
#define NWIN  (B_*T_)            // 2048 windows
#define NTOK  (NWIN*W_)          // 65536 token rows
#define FROWS 2176               // layer-0 qkv factor rows
#define SMALL (NWIN*D_)          // 2048x512 compact buffers (elems)

typedef __hip_bfloat16 bf16;
using bf16x8 = __attribute__((ext_vector_type(8))) short;   // MFMA A/B frag (4 VGPR)
using f32x4  = __attribute__((ext_vector_type(4))) float;   // 16x16 MFMA C/D frag
using f32x16 = __attribute__((ext_vector_type(16))) float;  // 32x32 MFMA C/D frag

// ---- memory plan (bytes): bf16-only residual stream ----------------------
#define XB_BYTES  ((size_t)NTOK * D_ * 2)     // 64 MiB bf16 residual master
#define WQ_ELEMS  ((size_t)L_ * 3*D_*D_)
#define WO_ELEMS  ((size_t)L_ * D_*D_)
#define W1_ELEMS  ((size_t)L_ * 4*D_*D_)
#define W2_ELEMS  ((size_t)L_ * 4*D_*D_)
#define WB_BYTES  ((WQ_ELEMS + WO_ELEMS + W1_ELEMS + W2_ELEMS) * 2)
#define FB_ELEMS  ((size_t)FROWS * D_)        // layer-0 factor input
#define QF_ELEMS  ((size_t)FROWS * 3*D_)      // layer-0 factor qkv
#define PPB_ELEMS ((size_t)W_ * 3*D_)         // fp32 pos+bias table
#define SCR_BYTES ((size_t)NTOK * 2560 * 2)   // qkv+ctx+y / h+y
#define TOTAL_BYTES (XB_BYTES + WB_BYTES + (FB_ELEMS + QF_ELEMS)*2 + PPB_ELEMS*4 + SCR_BYTES)

static char* g_fallback = nullptr;
__attribute__((constructor)) static void alloc_fallback() {
    (void)hipMalloc((void**)&g_fallback, TOTAL_BYTES);
}

// ---- async global->LDS (16B per lane; LDS dest = wave base + lane*16) -----
typedef __attribute__((address_space(3))) uint8_t* as3p;
typedef const __attribute__((address_space(1))) uint8_t* as1p;
__device__ __forceinline__ void gload_lds16(const void* g, void* l) {
    __builtin_amdgcn_global_load_lds((as1p)(const uint8_t*)g,
                                     (as3p)(uint32_t)(uintptr_t)l, 16, 0, 0);
}

__device__ __forceinline__ float bf2f(short s) {
    return __uint_as_float(((uint32_t)(uint16_t)s) << 16);
}
__device__ __forceinline__ short f2bf(float f) {
    return (short)__bfloat16_as_ushort(__float2bfloat16(f));
}

// ---------------------------------------------------------------------------
// weight convert fp32 -> bf16 (4 elems/thread)
// ---------------------------------------------------------------------------
__global__ __launch_bounds__(256) void cvt_kernel(
    const float* __restrict__ w, bf16* __restrict__ o, int n4)
{
    int i = blockIdx.x * 256 + threadIdx.x;
    if (i >= n4) return;
    float4 f = ((const float4*)w)[i];
    bf16* d = o + (size_t)i * 4;
    d[0] = __float2bfloat16(f.x);
    d[1] = __float2bfloat16(f.y);
    d[2] = __float2bfloat16(f.z);
    d[3] = __float2bfloat16(f.w);
}

// ---------------------------------------------------------------------------
// build_x: xb[n*32+w,:] = bf16(feats[b, max(t+w-31,0),:] + pos[w,:])
// ---------------------------------------------------------------------------
__global__ __launch_bounds__(256) void build_x_kernel(
    const float* __restrict__ feats,
    const float* __restrict__ pos,
    bf16* __restrict__ xb)
{
    int gid   = blockIdx.x * 256 + threadIdx.x;   // over NTOK * (D/4)
    int token = gid >> 7;
    int c4    = (gid & 127) * 4;
    int w     = token & (W_-1);
    int n     = token >> 5;
    int t     = n & (T_-1);
    int b     = n >> 8;
    int frame = t + w - (W_-1); if (frame < 0) frame = 0;
    const float4 f = *(const float4*)(feats + ((size_t)(b*T_ + frame)*D_ + c4));
    const float4 p = *(const float4*)(pos   + ((size_t)w*D_ + c4));
    bf16* d = xb + (size_t)token*D_ + c4;
    d[0] = __float2bfloat16(f.x + p.x);
    d[1] = __float2bfloat16(f.y + p.y);
    d[2] = __float2bfloat16(f.z + p.z);
    d[3] = __float2bfloat16(f.w + p.w);
}

// ---------------------------------------------------------------------------
// build_fb: factor matrix for layer-0 qkv.
// ---------------------------------------------------------------------------
__global__ __launch_bounds__(256) void build_fb_kernel(
    const float* __restrict__ feats,
    const float* __restrict__ pos,
    bf16* __restrict__ fb)
{
    int gid = blockIdx.x * 256 + threadIdx.x;     // over FROWS * (D/4)
    int row = gid >> 7;
    int c4  = (gid & 127) * 4;
    bf16* d = fb + (size_t)row * D_ + c4;
    float4 f;
    if (row < 2048)      f = *(const float4*)(feats + (size_t)row * D_ + c4);
    else if (row < 2080) f = *(const float4*)(pos + (size_t)(row - 2048) * D_ + c4);
    else                 f = make_float4(0.f, 0.f, 0.f, 0.f);
    d[0] = __float2bfloat16(f.x);
    d[1] = __float2bfloat16(f.y);
    d[2] = __float2bfloat16(f.z);
    d[3] = __float2bfloat16(f.w);
}

// ---------------------------------------------------------------------------
// build_ppb: ppb[w][c] = f32(qf[2048+w][c]) + bq[c]
// ---------------------------------------------------------------------------
__global__ __launch_bounds__(256) void build_ppb_kernel(
    const bf16* __restrict__ qf,
    const float* __restrict__ bq,
    float* __restrict__ ppb)
{
    int gid = blockIdx.x * 256 + threadIdx.x;   // over 32*1536
    int w = gid / (3*D_), c = gid % (3*D_);
    ppb[gid] = bf2f(*(const short*)(qf + (size_t)(2048 + w) * (3*D_) + c)) + bq[c];
}

// ---------------------------------------------------------------------------
// slice31: xg[n,:] = xb[n*32+31,:]
// ---------------------------------------------------------------------------
__global__ __launch_bounds__(256) void slice31_kernel(
    const bf16* __restrict__ xb, bf16* __restrict__ xg)
{
    int gid = blockIdx.x * 256 + threadIdx.x;   // over NWIN*64
    int n = gid >> 6, c0 = (gid & 63) * 8;
    *(bf16x8*)(xg + (size_t)n*D_ + c0) =
        *(const bf16x8*)(xb + (size_t)(n*W_ + (W_-1))*D_ + c0);
}

// ---------------------------------------------------------------------------
// 128x128 bf16 MFMA GEMM (32x32x16) — layer-0 factor GEMM, layer-3 smalls.
// ---------------------------------------------------------------------------
template<bool RELU, bool BIAS, bool REMAP>
__global__ __launch_bounds__(256) void gemm_bf16(
    const bf16* __restrict__ A,
    const bf16* __restrict__ Bt,
    const float* __restrict__ bias,
    bf16* __restrict__ Cb,
    int M, int N, int K)
{
    __shared__ bf16 As[128*32];
    __shared__ bf16 Bs[128*32];

    const int tid  = threadIdx.x;
    const int lane = tid & 63;
    const int wv   = tid >> 6;

    const int gridN = N >> 7;
    const int bid   = blockIdx.x;
    int m0, n0;
    if (REMAP) {
        const int q_ = bid >> 3;
        n0 = (q_ % gridN) << 7;
        m0 = (((q_ / gridN) * 8) + (bid & 7)) << 7;
    } else {
        n0 = (bid % gridN) << 7;
        m0 = (bid / gridN) << 7;
    }

    const int wm = (wv >> 1) * 64;
    const int wn = (wv & 1) * 64;

    f32x16 acc[2][2] = {};

    const int   srow  = wv*16 + (lane >> 2);
    const int   skoff = (lane & 3) * 8;
    const bf16* ga0 = A  + (size_t)(m0 + srow)      * K + skoff;
    const bf16* ga1 = A  + (size_t)(m0 + 64 + srow) * K + skoff;
    const bf16* gb0 = Bt + (size_t)(n0 + srow)      * K + skoff;
    const bf16* gb1 = Bt + (size_t)(n0 + 64 + srow) * K + skoff;
    char* lAs = (char*)As;
    char* lBs = (char*)Bs;
    const int l0 = wv*1024 + lane*16;

    const int r32  = lane & 31;
    const int ksel = (lane >> 5) * 16;

    for (int k0 = 0; k0 < K; k0 += 32) {
        gload_lds16(ga0 + k0, lAs + l0);
        gload_lds16(ga1 + k0, lAs + l0 + 4096);
        gload_lds16(gb0 + k0, lBs + l0);
        gload_lds16(gb1 + k0, lBs + l0 + 4096);
        __syncthreads();

        bf16x8 av[2][2], bv[2][2];
#pragma unroll
        for (int i = 0; i < 2; ++i)
#pragma unroll
            for (int h = 0; h < 2; ++h) {
                av[i][h] = *(const bf16x8*)(lAs + (wm + i*32 + r32)*64 + h*32 + ksel);
                bv[i][h] = *(const bf16x8*)(lBs + (wn + i*32 + r32)*64 + h*32 + ksel);
            }
#pragma unroll
        for (int i = 0; i < 2; ++i)
#pragma unroll
            for (int j = 0; j < 2; ++j) {
                acc[i][j] = __builtin_amdgcn_mfma_f32_32x32x16_bf16(
                    av[i][0], bv[j][0], acc[i][j], 0, 0, 0);
                acc[i][j] = __builtin_amdgcn_mfma_f32_32x32x16_bf16(
                    av[i][1], bv[j][1], acc[i][j], 0, 0, 0);
            }
        __syncthreads();
    }

    const int rbase = (lane >> 5) * 4;
#pragma unroll
    for (int i = 0; i < 2; ++i) {
#pragma unroll
        for (int j = 0; j < 2; ++j) {
            const int ncol = n0 + wn + j*32 + r32;
            const float bv_ = BIAS ? bias[ncol] : 0.f;
#pragma unroll
            for (int reg = 0; reg < 16; ++reg) {
                const int mrow = m0 + wm + i*32 + (reg & 3) + 8*(reg >> 2) + rbase;
                float v = acc[i][j][reg] + bv_;
                if (RELU) v = fmaxf(v, 0.f);
                Cb[(size_t)mrow * N + ncol] = __float2bfloat16(v);
            }
        }
    }
}

// ---------------------------------------------------------------------------
// 256x256 8-phase bf16 GEMM — r3-verified pipeline, panel-grouped XCD remap.
// Used for qkv (N=1536), layer-3 kv (N=1024), Wo (N=512).
// Requires M%256==0, N%256==0, K%128==0, (M/256)%8==0.
// ---------------------------------------------------------------------------
template<bool RELU, bool BIAS>
__global__ __launch_bounds__(512, 2) void gemm256(
    const bf16* __restrict__ A,
    const bf16* __restrict__ Bt,
    const float* __restrict__ bias,
    bf16* __restrict__ Cb,
    int M, int N, int K)
{
    (void)M;
    __shared__ bf16 As[2][256*64];   // 32 KiB per buffer
    __shared__ bf16 Bs[2][256*64];

    const int tid  = threadIdx.x;
    const int lane = tid & 63;
    const int wv   = tid >> 6;       // 0..7
    const int wm   = wv >> 2;        // 0..1 : M-wave (128 rows)
    const int wn   = wv & 3;         // 0..3 : N-wave (64 cols)
    const int L    = lane & 15;
    const int qd   = lane >> 4;      // 0..3

    // panel-grouped XCD remap
    const int gridN = N >> 8;
    const int W8  = gridN << 3;
    const int bid = blockIdx.x;
    const int q_  = bid / W8;
    const int r_  = bid % W8;
    const int n0  = (r_ >> 3) << 8;
    const int m0  = ((q_ << 3) + (r_ & 7)) << 8;

    const int srow = tid >> 3;
    const int scol = ((tid & 7) ^ (srow & 7)) * 8;   // elements
    const bf16* gA = A  + (size_t)(m0 + srow) * K + scol;
    const bf16* gB = Bt + (size_t)(n0 + srow) * K + scol;
    const size_t rstep = (size_t)64 * K;             // +64 rows
    bf16* lA = &As[0][0] + tid * 8;
    bf16* lB = &Bs[0][0] + tid * 8;

    const int physk0 = ((qd)     ^ (L & 7)) * 8;     // kk=0 chunk
    const int physk1 = ((4 + qd) ^ (L & 7)) * 8;     // kk=1 chunk
    const int aoff = (wm*128 + L) * 64;
    const int boff = (wn*64  + L) * 64;

    f32x4 acc[8][4] = {};
    bf16x8 av0[4][2], av1[4][2], bv0[2][2], bv1[2][2];

#define STAGE_A2(b, kt) do { \
    const bf16* s_ = gA + (size_t)(kt) * 64; \
    bf16* d_ = lA + (b) * 16384; \
    gload_lds16(s_,            d_); \
    gload_lds16(s_ +   rstep,  d_ + 4096); \
    gload_lds16(s_ + 2*rstep,  d_ + 8192); \
    gload_lds16(s_ + 3*rstep,  d_ + 12288); } while (0)

#define STAGE_B2(b, kt) do { \
    const bf16* s_ = gB + (size_t)(kt) * 64; \
    bf16* d_ = lB + (b) * 16384; \
    gload_lds16(s_,            d_); \
    gload_lds16(s_ +   rstep,  d_ + 4096); \
    gload_lds16(s_ + 2*rstep,  d_ + 8192); \
    gload_lds16(s_ + 3*rstep,  d_ + 12288); } while (0)

#define LDA_(dst, b, qm) do { \
    const bf16* pa_ = &As[b][aoff + (qm)*4096]; \
    _Pragma("unroll") \
    for (int mr_ = 0; mr_ < 4; ++mr_) { \
        dst[mr_][0] = *(const bf16x8*)(pa_ + mr_*1024 + physk0); \
        dst[mr_][1] = *(const bf16x8*)(pa_ + mr_*1024 + physk1); } } while (0)

#define LDB_(dst, b, qn) do { \
    const bf16* pb_ = &Bs[b][boff + (qn)*2048]; \
    _Pragma("unroll") \
    for (int nr_ = 0; nr_ < 2; ++nr_) { \
        dst[nr_][0] = *(const bf16x8*)(pb_ + nr_*1024 + physk0); \
        dst[nr_][1] = *(const bf16x8*)(pb_ + nr_*1024 + physk1); } } while (0)

#define MMA_(qm, qn, av, bv) do { \
    _Pragma("unroll") \
    for (int mr_ = 0; mr_ < 4; ++mr_) \
    _Pragma("unroll") \
    for (int nr_ = 0; nr_ < 2; ++nr_) { \
        f32x4 c_ = acc[(qm)*4+mr_][(qn)*2+nr_]; \
        c_ = __builtin_amdgcn_mfma_f32_16x16x32_bf16(av[mr_][0], bv[nr_][0], c_, 0, 0, 0); \
        c_ = __builtin_amdgcn_mfma_f32_16x16x32_bf16(av[mr_][1], bv[nr_][1], c_, 0, 0, 0); \
        acc[(qm)*4+mr_][(qn)*2+nr_] = c_; } } while (0)

#define BAR_ __builtin_amdgcn_s_barrier()
#define LGKM0_ do { asm volatile("s_waitcnt lgkmcnt(0)" ::: "memory"); \
                    __builtin_amdgcn_sched_barrier(0); } while (0)

#define TILE_(b, kt2) do { \
    /* P1 */ \
    LDA_(av0, b, 0); LDB_(bv0, b, 0); \
    BAR_; LGKM0_; \
    __builtin_amdgcn_s_setprio(1); MMA_(0, 0, av0, bv0); __builtin_amdgcn_s_setprio(0); \
    BAR_; \
    /* P2 */ \
    LDB_(bv1, b, 1); \
    BAR_; LGKM0_; \
    __builtin_amdgcn_s_setprio(1); MMA_(0, 1, av0, bv1); __builtin_amdgcn_s_setprio(0); \
    BAR_; \
    /* P3 */ \
    LDA_(av1, b, 1); \
    STAGE_B2(b, kt2); \
    BAR_; LGKM0_; \
    __builtin_amdgcn_s_setprio(1); MMA_(1, 1, av1, bv1); __builtin_amdgcn_s_setprio(0); \
    BAR_; \
    /* P4 */ \
    STAGE_A2(b, kt2); \
    __builtin_amdgcn_s_setprio(1); MMA_(1, 0, av1, bv0); __builtin_amdgcn_s_setprio(0); \
    asm volatile("s_waitcnt vmcnt(8)" ::: "memory"); \
    BAR_; } while (0)

    const int nkt = K >> 6;

    STAGE_B2(0, 0); STAGE_A2(0, 0);
    STAGE_B2(1, 1); STAGE_A2(1, 1);
    asm volatile("s_waitcnt vmcnt(8)" ::: "memory");
    BAR_;

    for (int u = 0; u < nkt; u += 2) {
        int k2 = u + 2; if (k2 >= nkt) k2 -= nkt;
        int k3 = u + 3; if (k3 >= nkt) k3 -= nkt;
        TILE_(0, k2);
        TILE_(1, k3);
    }

    asm volatile("s_waitcnt vmcnt(0)" ::: "memory");

#pragma unroll
    for (int mr = 0; mr < 8; ++mr) {
        const int row = m0 + wm*128 + mr*16 + qd*4;
#pragma unroll
        for (int nr = 0; nr < 4; ++nr) {
            const int col = n0 + wn*64 + nr*16 + L;
            const float bb = BIAS ? bias[col] : 0.f;
            bf16* cp = Cb + (size_t)row * N + col;
#pragma unroll
            for (int rg = 0; rg < 4; ++rg) {
                float v = acc[mr][nr][rg] + bb;
                if (RELU) v = fmaxf(v, 0.f);
                cp[(size_t)rg * N] = __float2bfloat16(v);
            }
        }
    }

#undef STAGE_A2
#undef STAGE_B2
#undef LDA_
#undef LDB_
#undef MMA_
#undef BAR_
#undef LGKM0_
#undef TILE_
}

// ---------------------------------------------------------------------------
// gemm256m: PERSISTENT-over-M variant of gemm256 (same TILE_ pipeline,
// byte-identical barrier/vmcnt structure) for W1 (N=2048) and W2 (N=512).
//   grid = 256 blocks (1/CU, ONE round). Block owns fixed n0 and sweeps
//   NPAN m-panels x nkt K-tiles as one flat pipelined tile stream:
//   prologue once per block (vs once per (m,n) tile); per-panel C-write
//   happens in-loop with NO drain (stores don't touch staged buffers;
//   next panel's stages already in flight) -> no round-tail serialization.
//   A is streamed exactly once (r2's refetch failure mode absent);
//   B slice (<=2MB weight) is L2/L3-served.
//   Mapping: SETS = 256/gridN; s = bid%SETS, n0 = (bid/SETS)<<8;
//   panel j -> m0 = (s + SETS*j)<<8. All gridN sharers of a panel have
//   bid ≡ s (mod 8)  [SETS multiple of 8] -> same XCD, same time-window.
// Requires (256/(N>>8)) % 8 == 0; K = 64<<LOG2NKT... K = (1<<LOG2NKT)*64.
// ---------------------------------------------------------------------------
template<bool RELU, int LOG2NKT, int NPAN>
__global__ __launch_bounds__(512, 2) void gemm256m(
    const bf16* __restrict__ A,
    const bf16* __restrict__ Bt,
    const float* __restrict__ bias,
    bf16* __restrict__ Cb,
    int N)
{
    constexpr int NKT = 1 << LOG2NKT;
    constexpr int K   = NKT * 64;
    constexpr int NT  = NPAN * NKT;   // flat tiles per block (even)

    __shared__ bf16 As[2][256*64];
    __shared__ bf16 Bs[2][256*64];

    const int tid  = threadIdx.x;
    const int lane = tid & 63;
    const int wv   = tid >> 6;
    const int wm   = wv >> 2;
    const int wn   = wv & 3;
    const int L    = lane & 15;
    const int qd   = lane >> 4;

    const int gridN = N >> 8;
    const int SETS  = 256 / gridN;     // 32 (W1) or 128 (W2); mult of 8
    const int bid   = blockIdx.x;
    const int sI    = bid % SETS;
    const int n0    = (bid / SETS) << 8;

    const int srow = tid >> 3;
    const int scol = ((tid & 7) ^ (srow & 7)) * 8;
    const bf16* gA0 = A  + (size_t)srow * K + scol;            // + panel row base
    const bf16* gB  = Bt + (size_t)(n0 + srow) * K + scol;
    const size_t rstep = (size_t)64 * K;
    bf16* lA = &As[0][0] + tid * 8;
    bf16* lB = &Bs[0][0] + tid * 8;

    const int physk0 = ((qd)     ^ (L & 7)) * 8;
    const int physk1 = ((4 + qd) ^ (L & 7)) * 8;
    const int aoff = (wm*128 + L) * 64;
    const int boff = (wn*64  + L) * 64;

    f32x4 acc[8][4] = {};
    bf16x8 av0[4][2], av1[4][2], bv0[2][2], bv1[2][2];

#define MSTAGE_A(b, tau) do { \
    const int p2_ = (tau) >> LOG2NKT, k2_ = (tau) & (NKT-1); \
    const bf16* s_ = gA0 + ((size_t)(sI + SETS*p2_) << 8) * K + (size_t)k2_ * 64; \
    bf16* d_ = lA + (b) * 16384; \
    gload_lds16(s_,            d_); \
    gload_lds16(s_ +   rstep,  d_ + 4096); \
    gload_lds16(s_ + 2*rstep,  d_ + 8192); \
    gload_lds16(s_ + 3*rstep,  d_ + 12288); } while (0)

#define MSTAGE_B(b, tau) do { \
    const bf16* s_ = gB + (size_t)((tau) & (NKT-1)) * 64; \
    bf16* d_ = lB + (b) * 16384; \
    gload_lds16(s_,            d_); \
    gload_lds16(s_ +   rstep,  d_ + 4096); \
    gload_lds16(s_ + 2*rstep,  d_ + 8192); \
    gload_lds16(s_ + 3*rstep,  d_ + 12288); } while (0)

#define MLDA(dst, b, qm) do { \
    const bf16* pa_ = &As[b][aoff + (qm)*4096]; \
    _Pragma("unroll") \
    for (int mr_ = 0; mr_ < 4; ++mr_) { \
        dst[mr_][0] = *(const bf16x8*)(pa_ + mr_*1024 + physk0); \
        dst[mr_][1] = *(const bf16x8*)(pa_ + mr_*1024 + physk1); } } while (0)

#define MLDB(dst, b, qn) do { \
    const bf16* pb_ = &Bs[b][boff + (qn)*2048]; \
    _Pragma("unroll") \
    for (int nr_ = 0; nr_ < 2; ++nr_) { \
        dst[nr_][0] = *(const bf16x8*)(pb_ + nr_*1024 + physk0); \
        dst[nr_][1] = *(const bf16x8*)(pb_ + nr_*1024 + physk1); } } while (0)

#define MMMA(qm, qn, av, bv) do { \
    _Pragma("unroll") \
    for (int mr_ = 0; mr_ < 4; ++mr_) \
    _Pragma("unroll") \
    for (int nr_ = 0; nr_ < 2; ++nr_) { \
        f32x4 c_ = acc[(qm)*4+mr_][(qn)*2+nr_]; \
        c_ = __builtin_amdgcn_mfma_f32_16x16x32_bf16(av[mr_][0], bv[nr_][0], c_, 0, 0, 0); \
        c_ = __builtin_amdgcn_mfma_f32_16x16x32_bf16(av[mr_][1], bv[nr_][1], c_, 0, 0, 0); \
        acc[(qm)*4+mr_][(qn)*2+nr_] = c_; } } while (0)

#define MBAR __builtin_amdgcn_s_barrier()
#define MLGKM0 do { asm volatile("s_waitcnt lgkmcnt(0)" ::: "memory"); \
                    __builtin_amdgcn_sched_barrier(0); } while (0)

#define MTILE(b, tau2) do { \
    /* P1 */ \
    MLDA(av0, b, 0); MLDB(bv0, b, 0); \
    MBAR; MLGKM0; \
    __builtin_amdgcn_s_setprio(1); MMMA(0, 0, av0, bv0); __builtin_amdgcn_s_setprio(0); \
    MBAR; \
    /* P2 */ \
    MLDB(bv1, b, 1); \
    MBAR; MLGKM0; \
    __builtin_amdgcn_s_setprio(1); MMMA(0, 1, av0, bv1); __builtin_amdgcn_s_setprio(0); \
    MBAR; \
    /* P3 */ \
    MLDA(av1, b, 1); \
    MSTAGE_B(b, tau2); \
    MBAR; MLGKM0; \
    __builtin_amdgcn_s_setprio(1); MMMA(1, 1, av1, bv1); __builtin_amdgcn_s_setprio(0); \
    MBAR; \
    /* P4 */ \
    MSTAGE_A(b, tau2); \
    __builtin_amdgcn_s_setprio(1); MMMA(1, 0, av1, bv0); __builtin_amdgcn_s_setprio(0); \
    asm volatile("s_waitcnt vmcnt(8)" ::: "memory"); \
    MBAR; } while (0)

    // prologue: stage flat tiles 0,1 (panel 0, kt 0/1); NKT>=8 so both panel 0
    MSTAGE_B(0, 0); MSTAGE_A(0, 0);
    MSTAGE_B(1, 1); MSTAGE_A(1, 1);
    asm volatile("s_waitcnt vmcnt(8)" ::: "memory");
    MBAR;

    for (int u = 0; u < NT; u += 2) {
        const int t2 = (u + 2 < NT) ? u + 2 : u;       // wrap: harmless restage
        const int t3 = (u + 3 < NT) ? u + 3 : u + 1;
        MTILE(0, t2);
        MTILE(1, t3);

        // panel epilogue: tile u+1 ends a panel iff (u+1) % NKT == NKT-1
        // (NKT even -> always odd tile). In-loop C-write, NO drain: stores
        // don't touch staged LDS; next panel's stages remain in flight.
        if (((u + 1) & (NKT - 1)) == NKT - 1) {
            const int panel = (u + 1) >> LOG2NKT;
            const int mbase = (sI + SETS * panel) << 8;
#pragma unroll
            for (int mr = 0; mr < 8; ++mr) {
                const int row = mbase + wm*128 + mr*16 + qd*4;
#pragma unroll
                for (int nr = 0; nr < 4; ++nr) {
                    const int col = n0 + wn*64 + nr*16 + L;
                    const float bb = bias[col];
                    bf16* cp = Cb + (size_t)row * N + col;
#pragma unroll
                    for (int rg = 0; rg < 4; ++rg) {
                        float v = acc[mr][nr][rg] + bb;
                        if (RELU) v = fmaxf(v, 0.f);
                        cp[(size_t)rg * N] = __float2bfloat16(v);
                    }
                    acc[mr][nr] = (f32x4){0.f, 0.f, 0.f, 0.f};
                }
            }
        }
    }

    asm volatile("s_waitcnt vmcnt(0)" ::: "memory");

#undef MSTAGE_A
#undef MSTAGE_B
#undef MLDA
#undef MLDB
#undef MMMA
#undef MBAR
#undef MLGKM0
#undef MTILE
}

// ---------------------------------------------------------------------------
// Fused residual-add + LayerNorm: xout = LN(y + xin) * g + b
// ---------------------------------------------------------------------------
__global__ __launch_bounds__(256) void lnres_kernel(
    const bf16* __restrict__ y,
    const bf16* __restrict__ xin,
    bf16* __restrict__ xout,
    const float* __restrict__ g,
    const float* __restrict__ b,
    int xin_stride)
{
    const int wave  = threadIdx.x >> 6;
    const int lane  = threadIdx.x & 63;
    const int token = blockIdx.x * 4 + wave;
    const int c0    = lane * 8;

    const bf16* yr = y    + (size_t)token * D_ + c0;
    const bf16* xr = xin  + (size_t)token * xin_stride + c0;
    bf16*       xo = xout + (size_t)token * D_ + c0;

    bf16x8 ty = *(const bf16x8*)yr;
    bf16x8 tx = *(const bf16x8*)xr;

    float v[8];
    float s1 = 0.f, s2 = 0.f;
#pragma unroll
    for (int j = 0; j < 8; ++j) {
        v[j] = bf2f(ty[j]) + bf2f(tx[j]);
        s1 += v[j]; s2 += v[j]*v[j];
    }
#pragma unroll
    for (int mask = 1; mask < 64; mask <<= 1) {
        s1 += __shfl_xor(s1, mask);
        s2 += __shfl_xor(s2, mask);
    }
    const float mu = s1 * (1.f / D_);
    float var = s2 * (1.f / D_) - mu * mu;
    if (var < 0.f) var = 0.f;
    const float rs = rsqrtf(var + 1e-5f);

    const float4 g0 = *(const float4*)(g + c0);
    const float4 g1 = *(const float4*)(g + c0 + 4);
    const float4 b0 = *(const float4*)(b + c0);
    const float4 b1 = *(const float4*)(b + c0 + 4);
    const float gg[8] = {g0.x,g0.y,g0.z,g0.w,g1.x,g1.y,g1.z,g1.w};
    const float bb[8] = {b0.x,b0.y,b0.z,b0.w,b1.x,b1.y,b1.z,b1.w};

    bf16x8 o;
#pragma unroll
    for (int j = 0; j < 8; ++j) {
        float t = (v[j] - mu) * rs * gg[j] + bb[j];
        o[j] = f2bf(t);
    }
    *(bf16x8*)xo = o;
}

// ---------------------------------------------------------------------------
// MFMA attention — one WAVE per (window, head). W=32, dh=64. (layers 1..2)
// ---------------------------------------------------------------------------
__global__ __launch_bounds__(256) void attn_mfma(
    const bf16* __restrict__ qkv,   // (NTOK, 1536)
    bf16* __restrict__ ctx)         // (NTOK, 512)
{
    __shared__ short Pb[4][32*32];

    const int tid  = threadIdx.x;
    const int lane = tid & 63;
    const int wv   = tid >> 6;
    const int pair = blockIdx.x * 4 + wv;
    const int win  = pair >> 3;
    const int h    = pair & 7;

    const int quad = lane >> 4;
    const int col  = lane & 15;

    const bf16* base = qkv + (size_t)win * W_ * (3*D_) + h * DH_;

    bf16x8 bvv[4];
    {
        const short* vbase = (const short*)(base + 2*D_);
#pragma unroll
        for (int ntd = 0; ntd < 4; ++ntd)
#pragma unroll
            for (int jj = 0; jj < 8; ++jj)
                bvv[ntd][jj] = vbase[(size_t)(quad*8 + jj) * (3*D_) + ntd*16 + col];
    }

    bf16x8 aq[2][2], bk[2][2];
#pragma unroll
    for (int mt = 0; mt < 2; ++mt)
#pragma unroll
        for (int kq = 0; kq < 2; ++kq)
            aq[mt][kq] = *(const bf16x8*)(base + (size_t)(mt*16 + col) * (3*D_)
                                          + kq*32 + quad*8);
#pragma unroll
    for (int nt = 0; nt < 2; ++nt)
#pragma unroll
        for (int kq = 0; kq < 2; ++kq)
            bk[nt][kq] = *(const bf16x8*)(base + D_ + (size_t)(nt*16 + col) * (3*D_)
                                          + kq*32 + quad*8);

    f32x4 S[2][2] = {};
#pragma unroll
    for (int mt = 0; mt < 2; ++mt)
#pragma unroll
        for (int nt = 0; nt < 2; ++nt) {
            S[mt][nt] = __builtin_amdgcn_mfma_f32_16x16x32_bf16(
                aq[mt][0], bk[nt][0], S[mt][nt], 0, 0, 0);
            S[mt][nt] = __builtin_amdgcn_mfma_f32_16x16x32_bf16(
                aq[mt][1], bk[nt][1], S[mt][nt], 0, 0, 0);
        }

    short* P = Pb[wv];
#pragma unroll
    for (int mt = 0; mt < 2; ++mt) {
#pragma unroll
        for (int reg = 0; reg < 4; ++reg) {
            const int row = mt*16 + quad*4 + reg;
            float v0 = (col      <= row) ? S[mt][0][reg] * 0.125f : -1e30f;
            float v1 = (16 + col <= row) ? S[mt][1][reg] * 0.125f : -1e30f;
            float mx = fmaxf(v0, v1);
#pragma unroll
            for (int m = 1; m < 16; m <<= 1) mx = fmaxf(mx, __shfl_xor(mx, m));
            float e0 = __expf(v0 - mx);
            float e1 = __expf(v1 - mx);
            float sm = e0 + e1;
#pragma unroll
            for (int m = 1; m < 16; m <<= 1) sm += __shfl_xor(sm, m);
            float inv = 1.f / sm;
            P[row*32 + col]      = f2bf(e0 * inv);
            P[row*32 + 16 + col] = f2bf(e1 * inv);
        }
    }

    bf16* cb = ctx + (size_t)win * W_ * D_ + h * DH_;
#pragma unroll
    for (int mt = 0; mt < 2; ++mt) {
        bf16x8 ap = *(const bf16x8*)(P + (mt*16 + col)*32 + quad*8);
#pragma unroll
        for (int ntd = 0; ntd < 4; ++ntd) {
            f32x4 O = {};
            O = __builtin_amdgcn_mfma_f32_16x16x32_bf16(ap, bvv[ntd], O, 0, 0, 0);
#pragma unroll
            for (int reg = 0; reg < 4; ++reg) {
                const int row = mt*16 + quad*4 + reg;
                cb[(size_t)row * D_ + ntd*16 + col] = __float2bfloat16(O[reg]);
            }
        }
    }
}

// ---------------------------------------------------------------------------
// attn_mfma0: layer-0 attention straight from the factor matrix.
// ---------------------------------------------------------------------------
__global__ __launch_bounds__(256) void attn_mfma0(
    const bf16* __restrict__ qf,    // (FROWS, 1536)
    const float* __restrict__ ppb,  // (32, 1536)
    bf16* __restrict__ ctx)         // (NTOK, 512)
{
    __shared__ short Pb[4][32*32];

    const int tid  = threadIdx.x;
    const int lane = tid & 63;
    const int wv   = tid >> 6;
    const int pair = blockIdx.x * 4 + wv;
    const int win  = pair >> 3;
    const int h    = pair & 7;

    const int quad = lane >> 4;
    const int col  = lane & 15;
    const int bb_  = win >> 8;
    const int tt_  = win & (T_-1);

#define FR_(w) ((size_t)(bb_*T_ + ((tt_ + (w) - (W_-1)) > 0 ? (tt_ + (w) - (W_-1)) : 0)) * (3*D_))

    bf16x8 bvv[4];
#pragma unroll
    for (int ntd = 0; ntd < 4; ++ntd)
#pragma unroll
        for (int jj = 0; jj < 8; ++jj) {
            const int w2 = quad*8 + jj;
            const int c  = 2*D_ + h*DH_ + ntd*16 + col;
            bvv[ntd][jj] = f2bf(bf2f(*(const short*)(qf + FR_(w2) + c))
                                + ppb[w2*(3*D_) + c]);
        }

    bf16x8 aq[2][2], bk[2][2];
#pragma unroll
    for (int mt = 0; mt < 2; ++mt)
#pragma unroll
        for (int kq = 0; kq < 2; ++kq) {
            const int w  = mt*16 + col;
            const size_t fro = FR_(w);
            const int cq = h*DH_ + kq*32 + quad*8;
            const bf16x8 a = *(const bf16x8*)(qf + fro + cq);
            const bf16x8 k = *(const bf16x8*)(qf + fro + D_ + cq);
            const float* pq = ppb + w*(3*D_) + cq;
            const float* pk = pq + D_;
#pragma unroll
            for (int j = 0; j < 8; ++j) {
                aq[mt][kq][j] = f2bf(bf2f(a[j]) + pq[j]);
                bk[mt][kq][j] = f2bf(bf2f(k[j]) + pk[j]);
            }
        }
#undef FR_

    f32x4 S[2][2] = {};
#pragma unroll
    for (int mt = 0; mt < 2; ++mt)
#pragma unroll
        for (int nt = 0; nt < 2; ++nt) {
            S[mt][nt] = __builtin_amdgcn_mfma_f32_16x16x32_bf16(
                aq[mt][0], bk[nt][0], S[mt][nt], 0, 0, 0);
            S[mt][nt] = __builtin_amdgcn_mfma_f32_16x16x32_bf16(
                aq[mt][1], bk[nt][1], S[mt][nt], 0, 0, 0);
        }

    short* P = Pb[wv];
#pragma unroll
    for (int mt = 0; mt < 2; ++mt) {
#pragma unroll
        for (int reg = 0; reg < 4; ++reg) {
            const int row = mt*16 + quad*4 + reg;
            float v0 = (col      <= row) ? S[mt][0][reg] * 0.125f : -1e30f;
            float v1 = (16 + col <= row) ? S[mt][1][reg] * 0.125f : -1e30f;
            float mx = fmaxf(v0, v1);
#pragma unroll
            for (int m = 1; m < 16; m <<= 1) mx = fmaxf(mx, __shfl_xor(mx, m));
            float e0 = __expf(v0 - mx);
            float e1 = __expf(v1 - mx);
            float sm = e0 + e1;
#pragma unroll
            for (int m = 1; m < 16; m <<= 1) sm += __shfl_xor(sm, m);
            float inv = 1.f / sm;
            P[row*32 + col]      = f2bf(e0 * inv);
            P[row*32 + 16 + col] = f2bf(e1 * inv);
        }
    }

    bf16* cb = ctx + (size_t)win * W_ * D_ + h * DH_;
#pragma unroll
    for (int mt = 0; mt < 2; ++mt) {
        bf16x8 ap = *(const bf16x8*)(P + (mt*16 + col)*32 + quad*8);
#pragma unroll
        for (int ntd = 0; ntd < 4; ++ntd) {
            f32x4 O = {};
            O = __builtin_amdgcn_mfma_f32_16x16x32_bf16(ap, bvv[ntd], O, 0, 0, 0);
#pragma unroll
            for (int reg = 0; reg < 4; ++reg) {
                const int row = mt*16 + quad*4 + reg;
                cb[(size_t)row * D_ + ntd*16 + col] = __float2bfloat16(O[reg]);
            }
        }
    }
}

// ---------------------------------------------------------------------------
// attn_last2: layer-3 attention, queries at w=31 only, split K/V input.
// ---------------------------------------------------------------------------
__global__ __launch_bounds__(256) void attn_last2(
    const bf16* __restrict__ kv,    // (NTOK, 1024) = [K|V]
    const bf16* __restrict__ q31,   // (NWIN, 512)
    bf16* __restrict__ ctxl)        // (NWIN, 512)
{
    __shared__ float Ps[4][32];

    const int wv   = threadIdx.x >> 6;
    const int lane = threadIdx.x & 63;
    const int pair = blockIdx.x * 4 + wv;
    const int win  = pair >> 3;
    const int h    = pair & 7;

    const bf16* kb   = kv + (size_t)win * W_ * 1024 + h * DH_;
    const short* qrow = (const short*)(q31 + (size_t)win * D_ + h * DH_);

    const int k    = lane & 31;
    const int half = lane >> 5;
    const short* krow = (const short*)(kb + (size_t)k * 1024 + half*32);

    float s = 0.f;
    const bf16x8* q8 = (const bf16x8*)(qrow + half*32);
    const bf16x8* k8 = (const bf16x8*)krow;
#pragma unroll
    for (int c = 0; c < 4; ++c) {
        bf16x8 qa = q8[c], kb_ = k8[c];
#pragma unroll
        for (int j = 0; j < 8; ++j) s += bf2f(qa[j]) * bf2f(kb_[j]);
    }
    s += __shfl_xor(s, 32);
    s *= 0.125f;

    float mx = s;
#pragma unroll
    for (int m = 1; m < 32; m <<= 1) mx = fmaxf(mx, __shfl_xor(mx, m));
    float e = __expf(s - mx);
    float sum = e;
#pragma unroll
    for (int m = 1; m < 32; m <<= 1) sum += __shfl_xor(sum, m);
    if (half == 0) Ps[wv][k] = e / sum;
    __syncthreads();

    const short* vb = (const short*)(kb + 512);
    float o = 0.f;
#pragma unroll
    for (int kk = 0; kk < 32; ++kk)
        o += Ps[wv][kk] * bf2f(vb[(size_t)kk * 1024 + lane]);

    ctxl[(size_t)win * D_ + h * DH_ + lane] = __float2bfloat16(o);
}

// ---------------------------------------------------------------------------
// Head: token = xq[n,:] bf16; logits (NWIN,6) then values (NWIN)
// ---------------------------------------------------------------------------
__global__ __launch_bounds__(64) void head_kernel(
    const bf16* __restrict__ xq,
    const float* __restrict__ Wp, const float* __restrict__ bp,
    const float* __restrict__ Wv, const float* __restrict__ bv,
    float* __restrict__ out)
{
    const int n    = blockIdx.x;
    const int lane = threadIdx.x;
    const bf16* row = xq + (size_t)n * D_;
    float t[8];
#pragma unroll
    for (int j = 0; j < 8; ++j) t[j] = bf2f(*(const short*)(row + lane + j*64));

    for (int a = 0; a < A_ + 1; ++a) {
        const float* w = (a < A_) ? (Wp + (size_t)a * D_) : Wv;
        float d = 0.f;
#pragma unroll
        for (int j = 0; j < 8; ++j) d += t[j] * w[lane + j*64];
#pragma unroll
        for (int off = 32; off > 0; off >>= 1) d += __shfl_down(d, off);
        if (lane == 0) {
            if (a < A_) out[(size_t)n*A_ + a] = d + bp[a];
            else        out[(size_t)NWIN*A_ + n] = d + bv[0];
        }
    }
}

// ---------------------------------------------------------------------------
extern "C" void kernel_launch(void* const* d_in, const int* in_sizes, int n_in,
                              void* d_out, int out_size, void* d_ws, size_t ws_size,
                              hipStream_t stream) {
    const float* feats = (const float*)d_in[0];
    const float* pos   = (const float*)d_in[1];
    const float* Wqkv  = (const float*)d_in[2];
    const float* bqkv  = (const float*)d_in[3];
    const float* Wo    = (const float*)d_in[4];
    const float* bo    = (const float*)d_in[5];
    const float* ln1g  = (const float*)d_in[6];
    const float* ln1b  = (const float*)d_in[7];
    const float* W1    = (const float*)d_in[8];
    const float* b1    = (const float*)d_in[9];
    const float* W2    = (const float*)d_in[10];
    const float* b2    = (const float*)d_in[11];
    const float* ln2g  = (const float*)d_in[12];
    const float* ln2b  = (const float*)d_in[13];
    const float* Wp    = (const float*)d_in[14];
    const float* bp    = (const float*)d_in[15];
    const float* Wv    = (const float*)d_in[16];
    const float* bv    = (const float*)d_in[17];
    float* out = (float*)d_out;

    char* basep = (ws_size >= TOTAL_BYTES) ? (char*)d_ws : g_fallback;

    bf16*  xb   = (bf16*)basep;
    bf16*  wq_b = (bf16*)(basep + XB_BYTES);
    bf16*  wo_b = wq_b + WQ_ELEMS;
    bf16*  w1_b = wo_b + WO_ELEMS;
    bf16*  w2_b = w1_b + W1_ELEMS;
    bf16*  fb   = w2_b + W2_ELEMS;                 // (FROWS, 512)
    bf16*  qf   = fb + FB_ELEMS;                   // (FROWS, 1536)
    float* ppb  = (float*)(qf + QF_ELEMS);         // (32, 1536) fp32
    bf16*  scr  = (bf16*)(ppb + PPB_ELEMS);
    bf16*  qkv_s = scr;                            // (NTOK, 1536) attn phase
    bf16*  kv_s  = scr;                            // (NTOK, 1024) layer-3
    bf16*  ctx_s = scr + (size_t)NTOK * (3*D_);    // (NTOK, 512)  attn phase
    bf16*  h_s   = scr;                            // (NTOK, 2048) FFN phase
    bf16*  y_s   = scr + (size_t)NTOK * 2048;      // (NTOK, 512)  both phases
    // layer-3 compact buffers, carved from ctx_s region
    bf16*  ctxl = ctx_s;                           // (NWIN, 512)
    bf16*  ysm  = ctx_s + (size_t)SMALL;           // (NWIN, 512)
    bf16*  hsm  = ctx_s + (size_t)2*SMALL;         // (NWIN, 2048)
    bf16*  xq   = ctx_s + (size_t)6*SMALL;         // (NWIN, 512)
    bf16*  xg   = ctx_s + (size_t)8*SMALL;         // (NWIN, 512) xb rows w=31
    bf16*  q31  = ctx_s + (size_t)9*SMALL;         // (NWIN, 512)

    cvt_kernel<<<(WQ_ELEMS/4 + 255)/256, 256, 0, stream>>>(Wqkv, wq_b, WQ_ELEMS/4);
    cvt_kernel<<<(WO_ELEMS/4 + 255)/256, 256, 0, stream>>>(Wo,   wo_b, WO_ELEMS/4);
    cvt_kernel<<<(W1_ELEMS/4 + 255)/256, 256, 0, stream>>>(W1,   w1_b, W1_ELEMS/4);
    cvt_kernel<<<(W2_ELEMS/4 + 255)/256, 256, 0, stream>>>(W2,   w2_b, W2_ELEMS/4);

    build_x_kernel<<<NTOK * (D_/4) / 256, 256, 0, stream>>>(feats, pos, xb);
    build_fb_kernel<<<FROWS * (D_/4) / 256, 256, 0, stream>>>(feats, pos, fb);

    const int GM2 = NTOK / 256;   // 256 m-panels (%8==0, remap ok)

    for (int i = 0; i < L_; ++i) {
        const bf16*  wq_i = wq_b + (size_t)i * 3*D_*D_;
        const float* bq_i = bqkv + (size_t)i * 3*D_;
        const bf16*  wo_i = wo_b + (size_t)i * D_*D_;
        const float* bo_i = bo   + (size_t)i * D_;
        const bf16*  w1_i = w1_b + (size_t)i * 4*D_*D_;
        const float* b1_i = b1   + (size_t)i * 4*D_;
        const bf16*  w2_i = w2_b + (size_t)i * 4*D_*D_;
        const float* b2_i = b2   + (size_t)i * D_;

        if (i == 0) {
            // layer-0 qkv via factors; attention reads qf directly.
            gemm_bf16<false,false,false><<<(FROWS/128) * (3*D_/128), 256, 0, stream>>>(
                fb, wq_i, nullptr, qf, FROWS, 3*D_, D_);
            build_ppb_kernel<<<W_*(3*D_)/256, 256, 0, stream>>>(qf, bq_i, ppb);
            attn_mfma0<<<NWIN * H_ / 4, 256, 0, stream>>>(qf, ppb, ctx_s);
        } else if (i < L_-1) {
            // qkv = xb @ Wqkv^T + bq : N=1536, K=512
            gemm256<false,true><<<GM2 * (3*D_/256), 512, 0, stream>>>(
                xb, wq_i, bq_i, qkv_s, NTOK, 3*D_, D_);
            attn_mfma<<<NWIN * H_ / 4, 256, 0, stream>>>(qkv_s, ctx_s);
        }

        if (i < L_-1) {
            // y = ctx @ Wo^T + bo : N=512, K=512
            gemm256<false,true><<<GM2 * (D_/256), 512, 0, stream>>>(
                ctx_s, wo_i, bo_i, y_s, NTOK, D_, D_);
            lnres_kernel<<<NTOK/4, 256, 0, stream>>>(
                y_s, xb, xb, ln1g + (size_t)i*D_, ln1b + (size_t)i*D_, D_);
            // h = relu(xb @ W1^T + b1) : N=2048, K=512 [persistent m-loop]
            gemm256m<true,3,8><<<256, 512, 0, stream>>>(
                xb, w1_i, b1_i, h_s, 4*D_);
            // y = h @ W2^T + b2 : N=512, K=2048 [persistent m-loop]
            gemm256m<false,5,2><<<256, 512, 0, stream>>>(
                h_s, w2_i, b2_i, y_s, D_);
            lnres_kernel<<<NTOK/4, 256, 0, stream>>>(
                y_s, xb, xb, ln2g + (size_t)i*D_, ln2b + (size_t)i*D_, D_);
        } else {
            // last layer: K/V for all tokens (N=1024), Q only at w=31.
            gemm256<false,true><<<GM2 * (1024/256), 512, 0, stream>>>(
                xb, wq_i + (size_t)D_*D_, bq_i + D_, kv_s, NTOK, 2*D_, D_);
            slice31_kernel<<<NWIN*64/256, 256, 0, stream>>>(xb, xg);
            gemm_bf16<false,true,false><<<(NWIN/128) * (D_/128), 256, 0, stream>>>(
                xg, wq_i, bq_i, q31, NWIN, D_, D_);
            attn_last2<<<NWIN * H_ / 4, 256, 0, stream>>>(kv_s, q31, ctxl);
            gemm_bf16<false,true,false><<<(NWIN/128) * (D_/128), 256, 0, stream>>>(
                ctxl, wo_i, bo_i, ysm, NWIN, D_, D_);
            lnres_kernel<<<NWIN/4, 256, 0, stream>>>(
                ysm, xg, xq,
                ln1g + (size_t)i*D_, ln1b + (size_t)i*D_, D_);
            gemm_bf16<true,true,false><<<(NWIN/128) * (4*D_/128), 256, 0, stream>>>(
                xq, w1_i, b1_i, hsm, NWIN, 4*D_, D_);
            gemm_bf16<false,true,false><<<(NWIN/128) * (D_/128), 256, 0, stream>>>(
                hsm, w2_i, b2_i, ysm, NWIN, D_, 4*D_);
            lnres_kernel<<<NWIN/4, 256, 0, stream>>>(
                ysm, xq, xq, ln2g + (size_t)i*D_, ln2b + (size_t)i*D_, D_);
        }
    }

    head_kernel<<<NWIN, 64, 0, stream>>>(xq, Wp, bp, Wv, bv, out);
}

// Round 9
// 1945.794 us; speedup vs baseline: 1.1491x; 1.0271x over previous
//
#include <hip/hip_runtime.h>
#include <hip/hip_bf16.h>
#include <cstdint>
#include <cstddef>

// Problem constants (fixed by reference)
#define B_    8
#define T_    256
#define D_    512
#define W_    32
#define L_    4
#define A_    6
#define H_    8
#define DH_   64
#define NWIN  (B_*T_)            // 2048 windows
#define NTOK  (NWIN*W_)          // 65536 token rows
#define FROWS 2176               // layer-0 qkv factor rows
#define SMALL (NWIN*D_)          // 2048x512 compact buffers (elems)

typedef __hip_bfloat16 bf16;
using bf16x8 = __attribute__((ext_vector_type(8))) short;   // MFMA A/B frag (4 VGPR)
using f32x4  = __attribute__((ext_vector_type(4))) float;   // 16x16 MFMA C/D frag
using f32x16 = __attribute__((ext_vector_type(16))) float;  // 32x32 MFMA C/D frag

// ---- memory plan (bytes): bf16-only residual stream ----------------------
#define XB_BYTES  ((size_t)NTOK * D_ * 2)     // 64 MiB bf16 residual master
#define WQ_ELEMS  ((size_t)L_ * 3*D_*D_)
#define WO_ELEMS  ((size_t)L_ * D_*D_)
#define W1_ELEMS  ((size_t)L_ * 4*D_*D_)
#define W2_ELEMS  ((size_t)L_ * 4*D_*D_)
#define WB_BYTES  ((WQ_ELEMS + WO_ELEMS + W1_ELEMS + W2_ELEMS) * 2)
#define FB_ELEMS  ((size_t)FROWS * D_)        // layer-0 factor input
#define QF_ELEMS  ((size_t)FROWS * 3*D_)      // layer-0 factor qkv
#define PPB_ELEMS ((size_t)W_ * 3*D_)         // fp32 pos+bias table
#define SCR_BYTES ((size_t)NTOK * 2560 * 2)   // qkv+ctx+y / h+y
#define TOTAL_BYTES (XB_BYTES + WB_BYTES + (FB_ELEMS + QF_ELEMS)*2 + PPB_ELEMS*4 + SCR_BYTES)

static char* g_fallback = nullptr;
__attribute__((constructor)) static void alloc_fallback() {
    (void)hipMalloc((void**)&g_fallback, TOTAL_BYTES);
}

// ---- async global->LDS (16B per lane; LDS dest = wave base + lane*16) -----
typedef __attribute__((address_space(3))) uint8_t* as3p;
typedef const __attribute__((address_space(1))) uint8_t* as1p;
__device__ __forceinline__ void gload_lds16(const void* g, void* l) {
    __builtin_amdgcn_global_load_lds((as1p)(const uint8_t*)g,
                                     (as3p)(uint32_t)(uintptr_t)l, 16, 0, 0);
}

__device__ __forceinline__ float bf2f(short s) {
    return __uint_as_float(((uint32_t)(uint16_t)s) << 16);
}
__device__ __forceinline__ short f2bf(float f) {
    return (short)__bfloat16_as_ushort(__float2bfloat16(f));
}

// ---------------------------------------------------------------------------
// weight convert fp32 -> bf16 (4 elems/thread)
// ---------------------------------------------------------------------------
__global__ __launch_bounds__(256) void cvt_kernel(
    const float* __restrict__ w, bf16* __restrict__ o, int n4)
{
    int i = blockIdx.x * 256 + threadIdx.x;
    if (i >= n4) return;
    float4 f = ((const float4*)w)[i];
    bf16* d = o + (size_t)i * 4;
    d[0] = __float2bfloat16(f.x);
    d[1] = __float2bfloat16(f.y);
    d[2] = __float2bfloat16(f.z);
    d[3] = __float2bfloat16(f.w);
}

// ---------------------------------------------------------------------------
// build_x: xb[n*32+w,:] = bf16(feats[b, max(t+w-31,0),:] + pos[w,:])
// ---------------------------------------------------------------------------
__global__ __launch_bounds__(256) void build_x_kernel(
    const float* __restrict__ feats,
    const float* __restrict__ pos,
    bf16* __restrict__ xb)
{
    int gid   = blockIdx.x * 256 + threadIdx.x;   // over NTOK * (D/4)
    int token = gid >> 7;
    int c4    = (gid & 127) * 4;
    int w     = token & (W_-1);
    int n     = token >> 5;
    int t     = n & (T_-1);
    int b     = n >> 8;
    int frame = t + w - (W_-1); if (frame < 0) frame = 0;
    const float4 f = *(const float4*)(feats + ((size_t)(b*T_ + frame)*D_ + c4));
    const float4 p = *(const float4*)(pos   + ((size_t)w*D_ + c4));
    bf16* d = xb + (size_t)token*D_ + c4;
    d[0] = __float2bfloat16(f.x + p.x);
    d[1] = __float2bfloat16(f.y + p.y);
    d[2] = __float2bfloat16(f.z + p.z);
    d[3] = __float2bfloat16(f.w + p.w);
}

// ---------------------------------------------------------------------------
// build_fb: factor matrix for layer-0 qkv.
// ---------------------------------------------------------------------------
__global__ __launch_bounds__(256) void build_fb_kernel(
    const float* __restrict__ feats,
    const float* __restrict__ pos,
    bf16* __restrict__ fb)
{
    int gid = blockIdx.x * 256 + threadIdx.x;     // over FROWS * (D/4)
    int row = gid >> 7;
    int c4  = (gid & 127) * 4;
    bf16* d = fb + (size_t)row * D_ + c4;
    float4 f;
    if (row < 2048)      f = *(const float4*)(feats + (size_t)row * D_ + c4);
    else if (row < 2080) f = *(const float4*)(pos + (size_t)(row - 2048) * D_ + c4);
    else                 f = make_float4(0.f, 0.f, 0.f, 0.f);
    d[0] = __float2bfloat16(f.x);
    d[1] = __float2bfloat16(f.y);
    d[2] = __float2bfloat16(f.z);
    d[3] = __float2bfloat16(f.w);
}

// ---------------------------------------------------------------------------
// build_ppb: ppb[w][c] = f32(qf[2048+w][c]) + bq[c]
// ---------------------------------------------------------------------------
__global__ __launch_bounds__(256) void build_ppb_kernel(
    const bf16* __restrict__ qf,
    const float* __restrict__ bq,
    float* __restrict__ ppb)
{
    int gid = blockIdx.x * 256 + threadIdx.x;   // over 32*1536
    int w = gid / (3*D_), c = gid % (3*D_);
    ppb[gid] = bf2f(*(const short*)(qf + (size_t)(2048 + w) * (3*D_) + c)) + bq[c];
}

// ---------------------------------------------------------------------------
// slice31: xg[n,:] = xb[n*32+31,:]
// ---------------------------------------------------------------------------
__global__ __launch_bounds__(256) void slice31_kernel(
    const bf16* __restrict__ xb, bf16* __restrict__ xg)
{
    int gid = blockIdx.x * 256 + threadIdx.x;   // over NWIN*64
    int n = gid >> 6, c0 = (gid & 63) * 8;
    *(bf16x8*)(xg + (size_t)n*D_ + c0) =
        *(const bf16x8*)(xb + (size_t)(n*W_ + (W_-1))*D_ + c0);
}

// ---------------------------------------------------------------------------
// 128x128 bf16 MFMA GEMM (32x32x16) — layer-0 factor GEMM, layer-3 smalls.
// ---------------------------------------------------------------------------
template<bool RELU, bool BIAS, bool REMAP>
__global__ __launch_bounds__(256) void gemm_bf16(
    const bf16* __restrict__ A,
    const bf16* __restrict__ Bt,
    const float* __restrict__ bias,
    bf16* __restrict__ Cb,
    int M, int N, int K)
{
    __shared__ bf16 As[128*32];
    __shared__ bf16 Bs[128*32];

    const int tid  = threadIdx.x;
    const int lane = tid & 63;
    const int wv   = tid >> 6;

    const int gridN = N >> 7;
    const int bid   = blockIdx.x;
    int m0, n0;
    if (REMAP) {
        const int q_ = bid >> 3;
        n0 = (q_ % gridN) << 7;
        m0 = (((q_ / gridN) * 8) + (bid & 7)) << 7;
    } else {
        n0 = (bid % gridN) << 7;
        m0 = (bid / gridN) << 7;
    }

    const int wm = (wv >> 1) * 64;
    const int wn = (wv & 1) * 64;

    f32x16 acc[2][2] = {};

    const int   srow  = wv*16 + (lane >> 2);
    const int   skoff = (lane & 3) * 8;
    const bf16* ga0 = A  + (size_t)(m0 + srow)      * K + skoff;
    const bf16* ga1 = A  + (size_t)(m0 + 64 + srow) * K + skoff;
    const bf16* gb0 = Bt + (size_t)(n0 + srow)      * K + skoff;
    const bf16* gb1 = Bt + (size_t)(n0 + 64 + srow) * K + skoff;
    char* lAs = (char*)As;
    char* lBs = (char*)Bs;
    const int l0 = wv*1024 + lane*16;

    const int r32  = lane & 31;
    const int ksel = (lane >> 5) * 16;

    for (int k0 = 0; k0 < K; k0 += 32) {
        gload_lds16(ga0 + k0, lAs + l0);
        gload_lds16(ga1 + k0, lAs + l0 + 4096);
        gload_lds16(gb0 + k0, lBs + l0);
        gload_lds16(gb1 + k0, lBs + l0 + 4096);
        __syncthreads();

        bf16x8 av[2][2], bv[2][2];
#pragma unroll
        for (int i = 0; i < 2; ++i)
#pragma unroll
            for (int h = 0; h < 2; ++h) {
                av[i][h] = *(const bf16x8*)(lAs + (wm + i*32 + r32)*64 + h*32 + ksel);
                bv[i][h] = *(const bf16x8*)(lBs + (wn + i*32 + r32)*64 + h*32 + ksel);
            }
#pragma unroll
        for (int i = 0; i < 2; ++i)
#pragma unroll
            for (int j = 0; j < 2; ++j) {
                acc[i][j] = __builtin_amdgcn_mfma_f32_32x32x16_bf16(
                    av[i][0], bv[j][0], acc[i][j], 0, 0, 0);
                acc[i][j] = __builtin_amdgcn_mfma_f32_32x32x16_bf16(
                    av[i][1], bv[j][1], acc[i][j], 0, 0, 0);
            }
        __syncthreads();
    }

    const int rbase = (lane >> 5) * 4;
#pragma unroll
    for (int i = 0; i < 2; ++i) {
#pragma unroll
        for (int j = 0; j < 2; ++j) {
            const int ncol = n0 + wn + j*32 + r32;
            const float bv_ = BIAS ? bias[ncol] : 0.f;
#pragma unroll
            for (int reg = 0; reg < 16; ++reg) {
                const int mrow = m0 + wm + i*32 + (reg & 3) + 8*(reg >> 2) + rbase;
                float v = acc[i][j][reg] + bv_;
                if (RELU) v = fmaxf(v, 0.f);
                Cb[(size_t)mrow * N + ncol] = __float2bfloat16(v);
            }
        }
    }
}

// ---------------------------------------------------------------------------
// gemm256m: PERSISTENT-over-M 256x256 8-phase GEMM (r8-verified: W1 161 µs /
// MfmaUtil 36.7% vs 180/32.4 per-tile).  Now used for ALL large GEMMs.
//   grid = 256 blocks (1/CU, ONE round). Block owns fixed n0 and sweeps
//   NPAN m-panels x NKT K-tiles as one flat pipelined tile stream; prologue
//   once per block; per-panel C-write in-loop with NO drain.
//   ldC: output row stride (lets Q / KV GEMMs write into one (NTOK,1536)
//   buffer at a column offset — caller passes Cb+colofs and bias+colofs).
//   Mapping: SETS = 256/gridN (gridN = N>>8; SETS must be mult of 8);
//   sI = bid%SETS, n0 = (bid/SETS)<<8; panel j -> m0 = (sI + SETS*j)<<8.
//   All sharers of a panel have bid ≡ sI (mod 8) -> same XCD window.
// ---------------------------------------------------------------------------
template<bool RELU, int LOG2NKT, int NPAN>
__global__ __launch_bounds__(512, 2) void gemm256m(
    const bf16* __restrict__ A,
    const bf16* __restrict__ Bt,
    const float* __restrict__ bias,
    bf16* __restrict__ Cb,
    int N, int ldC)
{
    constexpr int NKT = 1 << LOG2NKT;
    constexpr int K   = NKT * 64;
    constexpr int NT  = NPAN * NKT;   // flat tiles per block (even)

    __shared__ bf16 As[2][256*64];
    __shared__ bf16 Bs[2][256*64];

    const int tid  = threadIdx.x;
    const int lane = tid & 63;
    const int wv   = tid >> 6;
    const int wm   = wv >> 2;
    const int wn   = wv & 3;
    const int L    = lane & 15;
    const int qd   = lane >> 4;

    const int gridN = N >> 8;
    const int SETS  = 256 / gridN;     // mult of 8 for all our shapes
    const int bid   = blockIdx.x;
    const int sI    = bid % SETS;
    const int n0    = (bid / SETS) << 8;

    const int srow = tid >> 3;
    const int scol = ((tid & 7) ^ (srow & 7)) * 8;
    const bf16* gA0 = A  + (size_t)srow * K + scol;            // + panel row base
    const bf16* gB  = Bt + (size_t)(n0 + srow) * K + scol;
    const size_t rstep = (size_t)64 * K;
    bf16* lA = &As[0][0] + tid * 8;
    bf16* lB = &Bs[0][0] + tid * 8;

    const int physk0 = ((qd)     ^ (L & 7)) * 8;
    const int physk1 = ((4 + qd) ^ (L & 7)) * 8;
    const int aoff = (wm*128 + L) * 64;
    const int boff = (wn*64  + L) * 64;

    f32x4 acc[8][4] = {};
    bf16x8 av0[4][2], av1[4][2], bv0[2][2], bv1[2][2];

#define MSTAGE_A(b, tau) do { \
    const int p2_ = (tau) >> LOG2NKT, k2_ = (tau) & (NKT-1); \
    const bf16* s_ = gA0 + ((size_t)(sI + SETS*p2_) << 8) * K + (size_t)k2_ * 64; \
    bf16* d_ = lA + (b) * 16384; \
    gload_lds16(s_,            d_); \
    gload_lds16(s_ +   rstep,  d_ + 4096); \
    gload_lds16(s_ + 2*rstep,  d_ + 8192); \
    gload_lds16(s_ + 3*rstep,  d_ + 12288); } while (0)

#define MSTAGE_B(b, tau) do { \
    const bf16* s_ = gB + (size_t)((tau) & (NKT-1)) * 64; \
    bf16* d_ = lB + (b) * 16384; \
    gload_lds16(s_,            d_); \
    gload_lds16(s_ +   rstep,  d_ + 4096); \
    gload_lds16(s_ + 2*rstep,  d_ + 8192); \
    gload_lds16(s_ + 3*rstep,  d_ + 12288); } while (0)

#define MLDA(dst, b, qm) do { \
    const bf16* pa_ = &As[b][aoff + (qm)*4096]; \
    _Pragma("unroll") \
    for (int mr_ = 0; mr_ < 4; ++mr_) { \
        dst[mr_][0] = *(const bf16x8*)(pa_ + mr_*1024 + physk0); \
        dst[mr_][1] = *(const bf16x8*)(pa_ + mr_*1024 + physk1); } } while (0)

#define MLDB(dst, b, qn) do { \
    const bf16* pb_ = &Bs[b][boff + (qn)*2048]; \
    _Pragma("unroll") \
    for (int nr_ = 0; nr_ < 2; ++nr_) { \
        dst[nr_][0] = *(const bf16x8*)(pb_ + nr_*1024 + physk0); \
        dst[nr_][1] = *(const bf16x8*)(pb_ + nr_*1024 + physk1); } } while (0)

#define MMMA(qm, qn, av, bv) do { \
    _Pragma("unroll") \
    for (int mr_ = 0; mr_ < 4; ++mr_) \
    _Pragma("unroll") \
    for (int nr_ = 0; nr_ < 2; ++nr_) { \
        f32x4 c_ = acc[(qm)*4+mr_][(qn)*2+nr_]; \
        c_ = __builtin_amdgcn_mfma_f32_16x16x32_bf16(av[mr_][0], bv[nr_][0], c_, 0, 0, 0); \
        c_ = __builtin_amdgcn_mfma_f32_16x16x32_bf16(av[mr_][1], bv[nr_][1], c_, 0, 0, 0); \
        acc[(qm)*4+mr_][(qn)*2+nr_] = c_; } } while (0)

#define MBAR __builtin_amdgcn_s_barrier()
#define MLGKM0 do { asm volatile("s_waitcnt lgkmcnt(0)" ::: "memory"); \
                    __builtin_amdgcn_sched_barrier(0); } while (0)

#define MTILE(b, tau2) do { \
    /* P1 */ \
    MLDA(av0, b, 0); MLDB(bv0, b, 0); \
    MBAR; MLGKM0; \
    __builtin_amdgcn_s_setprio(1); MMMA(0, 0, av0, bv0); __builtin_amdgcn_s_setprio(0); \
    MBAR; \
    /* P2 */ \
    MLDB(bv1, b, 1); \
    MBAR; MLGKM0; \
    __builtin_amdgcn_s_setprio(1); MMMA(0, 1, av0, bv1); __builtin_amdgcn_s_setprio(0); \
    MBAR; \
    /* P3 */ \
    MLDA(av1, b, 1); \
    MSTAGE_B(b, tau2); \
    MBAR; MLGKM0; \
    __builtin_amdgcn_s_setprio(1); MMMA(1, 1, av1, bv1); __builtin_amdgcn_s_setprio(0); \
    MBAR; \
    /* P4 */ \
    MSTAGE_A(b, tau2); \
    __builtin_amdgcn_s_setprio(1); MMMA(1, 0, av1, bv0); __builtin_amdgcn_s_setprio(0); \
    asm volatile("s_waitcnt vmcnt(8)" ::: "memory"); \
    MBAR; } while (0)

    // prologue: stage flat tiles 0,1 (panel 0, kt 0/1)
    MSTAGE_B(0, 0); MSTAGE_A(0, 0);
    MSTAGE_B(1, 1); MSTAGE_A(1, 1);
    asm volatile("s_waitcnt vmcnt(8)" ::: "memory");
    MBAR;

    for (int u = 0; u < NT; u += 2) {
        const int t2 = (u + 2 < NT) ? u + 2 : u;       // wrap: harmless restage
        const int t3 = (u + 3 < NT) ? u + 3 : u + 1;
        MTILE(0, t2);
        MTILE(1, t3);

        // panel epilogue: tile u+1 ends a panel iff (u+1) % NKT == NKT-1
        // (NKT even -> always an odd tile). In-loop C-write, NO drain.
        if (((u + 1) & (NKT - 1)) == NKT - 1) {
            const int panel = (u + 1) >> LOG2NKT;
            const int mbase = (sI + SETS * panel) << 8;
#pragma unroll
            for (int mr = 0; mr < 8; ++mr) {
                const int row = mbase + wm*128 + mr*16 + qd*4;
#pragma unroll
                for (int nr = 0; nr < 4; ++nr) {
                    const int col = n0 + wn*64 + nr*16 + L;
                    const float bb = bias[col];
                    bf16* cp = Cb + (size_t)row * ldC + col;
#pragma unroll
                    for (int rg = 0; rg < 4; ++rg) {
                        float v = acc[mr][nr][rg] + bb;
                        if (RELU) v = fmaxf(v, 0.f);
                        cp[(size_t)rg * ldC] = __float2bfloat16(v);
                    }
                    acc[mr][nr] = (f32x4){0.f, 0.f, 0.f, 0.f};
                }
            }
        }
    }

    asm volatile("s_waitcnt vmcnt(0)" ::: "memory");

#undef MSTAGE_A
#undef MSTAGE_B
#undef MLDA
#undef MLDB
#undef MMMA
#undef MBAR
#undef MLGKM0
#undef MTILE
}

// ---------------------------------------------------------------------------
// Fused residual-add + LayerNorm: xout = LN(y + xin) * g + b
// ---------------------------------------------------------------------------
__global__ __launch_bounds__(256) void lnres_kernel(
    const bf16* __restrict__ y,
    const bf16* __restrict__ xin,
    bf16* __restrict__ xout,
    const float* __restrict__ g,
    const float* __restrict__ b,
    int xin_stride)
{
    const int wave  = threadIdx.x >> 6;
    const int lane  = threadIdx.x & 63;
    const int token = blockIdx.x * 4 + wave;
    const int c0    = lane * 8;

    const bf16* yr = y    + (size_t)token * D_ + c0;
    const bf16* xr = xin  + (size_t)token * xin_stride + c0;
    bf16*       xo = xout + (size_t)token * D_ + c0;

    bf16x8 ty = *(const bf16x8*)yr;
    bf16x8 tx = *(const bf16x8*)xr;

    float v[8];
    float s1 = 0.f, s2 = 0.f;
#pragma unroll
    for (int j = 0; j < 8; ++j) {
        v[j] = bf2f(ty[j]) + bf2f(tx[j]);
        s1 += v[j]; s2 += v[j]*v[j];
    }
#pragma unroll
    for (int mask = 1; mask < 64; mask <<= 1) {
        s1 += __shfl_xor(s1, mask);
        s2 += __shfl_xor(s2, mask);
    }
    const float mu = s1 * (1.f / D_);
    float var = s2 * (1.f / D_) - mu * mu;
    if (var < 0.f) var = 0.f;
    const float rs = rsqrtf(var + 1e-5f);

    const float4 g0 = *(const float4*)(g + c0);
    const float4 g1 = *(const float4*)(g + c0 + 4);
    const float4 b0 = *(const float4*)(b + c0);
    const float4 b1 = *(const float4*)(b + c0 + 4);
    const float gg[8] = {g0.x,g0.y,g0.z,g0.w,g1.x,g1.y,g1.z,g1.w};
    const float bb[8] = {b0.x,b0.y,b0.z,b0.w,b1.x,b1.y,b1.z,b1.w};

    bf16x8 o;
#pragma unroll
    for (int j = 0; j < 8; ++j) {
        float t = (v[j] - mu) * rs * gg[j] + bb[j];
        o[j] = f2bf(t);
    }
    *(bf16x8*)xo = o;
}

// ---------------------------------------------------------------------------
// MFMA attention — one WAVE per (window, head). W=32, dh=64. (layers 1..2)
// ---------------------------------------------------------------------------
__global__ __launch_bounds__(256) void attn_mfma(
    const bf16* __restrict__ qkv,   // (NTOK, 1536)
    bf16* __restrict__ ctx)         // (NTOK, 512)
{
    __shared__ short Pb[4][32*32];

    const int tid  = threadIdx.x;
    const int lane = tid & 63;
    const int wv   = tid >> 6;
    const int pair = blockIdx.x * 4 + wv;
    const int win  = pair >> 3;
    const int h    = pair & 7;

    const int quad = lane >> 4;
    const int col  = lane & 15;

    const bf16* base = qkv + (size_t)win * W_ * (3*D_) + h * DH_;

    bf16x8 bvv[4];
    {
        const short* vbase = (const short*)(base + 2*D_);
#pragma unroll
        for (int ntd = 0; ntd < 4; ++ntd)
#pragma unroll
            for (int jj = 0; jj < 8; ++jj)
                bvv[ntd][jj] = vbase[(size_t)(quad*8 + jj) * (3*D_) + ntd*16 + col];
    }

    bf16x8 aq[2][2], bk[2][2];
#pragma unroll
    for (int mt = 0; mt < 2; ++mt)
#pragma unroll
        for (int kq = 0; kq < 2; ++kq)
            aq[mt][kq] = *(const bf16x8*)(base + (size_t)(mt*16 + col) * (3*D_)
                                          + kq*32 + quad*8);
#pragma unroll
    for (int nt = 0; nt < 2; ++nt)
#pragma unroll
        for (int kq = 0; kq < 2; ++kq)
            bk[nt][kq] = *(const bf16x8*)(base + D_ + (size_t)(nt*16 + col) * (3*D_)
                                          + kq*32 + quad*8);

    f32x4 S[2][2] = {};
#pragma unroll
    for (int mt = 0; mt < 2; ++mt)
#pragma unroll
        for (int nt = 0; nt < 2; ++nt) {
            S[mt][nt] = __builtin_amdgcn_mfma_f32_16x16x32_bf16(
                aq[mt][0], bk[nt][0], S[mt][nt], 0, 0, 0);
            S[mt][nt] = __builtin_amdgcn_mfma_f32_16x16x32_bf16(
                aq[mt][1], bk[nt][1], S[mt][nt], 0, 0, 0);
        }

    short* P = Pb[wv];
#pragma unroll
    for (int mt = 0; mt < 2; ++mt) {
#pragma unroll
        for (int reg = 0; reg < 4; ++reg) {
            const int row = mt*16 + quad*4 + reg;
            float v0 = (col      <= row) ? S[mt][0][reg] * 0.125f : -1e30f;
            float v1 = (16 + col <= row) ? S[mt][1][reg] * 0.125f : -1e30f;
            float mx = fmaxf(v0, v1);
#pragma unroll
            for (int m = 1; m < 16; m <<= 1) mx = fmaxf(mx, __shfl_xor(mx, m));
            float e0 = __expf(v0 - mx);
            float e1 = __expf(v1 - mx);
            float sm = e0 + e1;
#pragma unroll
            for (int m = 1; m < 16; m <<= 1) sm += __shfl_xor(sm, m);
            float inv = 1.f / sm;
            P[row*32 + col]      = f2bf(e0 * inv);
            P[row*32 + 16 + col] = f2bf(e1 * inv);
        }
    }

    bf16* cb = ctx + (size_t)win * W_ * D_ + h * DH_;
#pragma unroll
    for (int mt = 0; mt < 2; ++mt) {
        bf16x8 ap = *(const bf16x8*)(P + (mt*16 + col)*32 + quad*8);
#pragma unroll
        for (int ntd = 0; ntd < 4; ++ntd) {
            f32x4 O = {};
            O = __builtin_amdgcn_mfma_f32_16x16x32_bf16(ap, bvv[ntd], O, 0, 0, 0);
#pragma unroll
            for (int reg = 0; reg < 4; ++reg) {
                const int row = mt*16 + quad*4 + reg;
                cb[(size_t)row * D_ + ntd*16 + col] = __float2bfloat16(O[reg]);
            }
        }
    }
}

// ---------------------------------------------------------------------------
// attn_mfma0: layer-0 attention straight from the factor matrix.
// ---------------------------------------------------------------------------
__global__ __launch_bounds__(256) void attn_mfma0(
    const bf16* __restrict__ qf,    // (FROWS, 1536)
    const float* __restrict__ ppb,  // (32, 1536)
    bf16* __restrict__ ctx)         // (NTOK, 512)
{
    __shared__ short Pb[4][32*32];

    const int tid  = threadIdx.x;
    const int lane = tid & 63;
    const int wv   = tid >> 6;
    const int pair = blockIdx.x * 4 + wv;
    const int win  = pair >> 3;
    const int h    = pair & 7;

    const int quad = lane >> 4;
    const int col  = lane & 15;
    const int bb_  = win >> 8;
    const int tt_  = win & (T_-1);

#define FR_(w) ((size_t)(bb_*T_ + ((tt_ + (w) - (W_-1)) > 0 ? (tt_ + (w) - (W_-1)) : 0)) * (3*D_))

    bf16x8 bvv[4];
#pragma unroll
    for (int ntd = 0; ntd < 4; ++ntd)
#pragma unroll
        for (int jj = 0; jj < 8; ++jj) {
            const int w2 = quad*8 + jj;
            const int c  = 2*D_ + h*DH_ + ntd*16 + col;
            bvv[ntd][jj] = f2bf(bf2f(*(const short*)(qf + FR_(w2) + c))
                                + ppb[w2*(3*D_) + c]);
        }

    bf16x8 aq[2][2], bk[2][2];
#pragma unroll
    for (int mt = 0; mt < 2; ++mt)
#pragma unroll
        for (int kq = 0; kq < 2; ++kq) {
            const int w  = mt*16 + col;
            const size_t fro = FR_(w);
            const int cq = h*DH_ + kq*32 + quad*8;
            const bf16x8 a = *(const bf16x8*)(qf + fro + cq);
            const bf16x8 k = *(const bf16x8*)(qf + fro + D_ + cq);
            const float* pq = ppb + w*(3*D_) + cq;
            const float* pk = pq + D_;
#pragma unroll
            for (int j = 0; j < 8; ++j) {
                aq[mt][kq][j] = f2bf(bf2f(a[j]) + pq[j]);
                bk[mt][kq][j] = f2bf(bf2f(k[j]) + pk[j]);
            }
        }
#undef FR_

    f32x4 S[2][2] = {};
#pragma unroll
    for (int mt = 0; mt < 2; ++mt)
#pragma unroll
        for (int nt = 0; nt < 2; ++nt) {
            S[mt][nt] = __builtin_amdgcn_mfma_f32_16x16x32_bf16(
                aq[mt][0], bk[nt][0], S[mt][nt], 0, 0, 0);
            S[mt][nt] = __builtin_amdgcn_mfma_f32_16x16x32_bf16(
                aq[mt][1], bk[nt][1], S[mt][nt], 0, 0, 0);
        }

    short* P = Pb[wv];
#pragma unroll
    for (int mt = 0; mt < 2; ++mt) {
#pragma unroll
        for (int reg = 0; reg < 4; ++reg) {
            const int row = mt*16 + quad*4 + reg;
            float v0 = (col      <= row) ? S[mt][0][reg] * 0.125f : -1e30f;
            float v1 = (16 + col <= row) ? S[mt][1][reg] * 0.125f : -1e30f;
            float mx = fmaxf(v0, v1);
#pragma unroll
            for (int m = 1; m < 16; m <<= 1) mx = fmaxf(mx, __shfl_xor(mx, m));
            float e0 = __expf(v0 - mx);
            float e1 = __expf(v1 - mx);
            float sm = e0 + e1;
#pragma unroll
            for (int m = 1; m < 16; m <<= 1) sm += __shfl_xor(sm, m);
            float inv = 1.f / sm;
            P[row*32 + col]      = f2bf(e0 * inv);
            P[row*32 + 16 + col] = f2bf(e1 * inv);
        }
    }

    bf16* cb = ctx + (size_t)win * W_ * D_ + h * DH_;
#pragma unroll
    for (int mt = 0; mt < 2; ++mt) {
        bf16x8 ap = *(const bf16x8*)(P + (mt*16 + col)*32 + quad*8);
#pragma unroll
        for (int ntd = 0; ntd < 4; ++ntd) {
            f32x4 O = {};
            O = __builtin_amdgcn_mfma_f32_16x16x32_bf16(ap, bvv[ntd], O, 0, 0, 0);
#pragma unroll
            for (int reg = 0; reg < 4; ++reg) {
                const int row = mt*16 + quad*4 + reg;
                cb[(size_t)row * D_ + ntd*16 + col] = __float2bfloat16(O[reg]);
            }
        }
    }
}

// ---------------------------------------------------------------------------
// attn_last2: layer-3 attention, queries at w=31 only, split K/V input.
// ---------------------------------------------------------------------------
__global__ __launch_bounds__(256) void attn_last2(
    const bf16* __restrict__ kv,    // (NTOK, 1024) = [K|V]
    const bf16* __restrict__ q31,   // (NWIN, 512)
    bf16* __restrict__ ctxl)        // (NWIN, 512)
{
    __shared__ float Ps[4][32];

    const int wv   = threadIdx.x >> 6;
    const int lane = threadIdx.x & 63;
    const int pair = blockIdx.x * 4 + wv;
    const int win  = pair >> 3;
    const int h    = pair & 7;

    const bf16* kb   = kv + (size_t)win * W_ * 1024 + h * DH_;
    const short* qrow = (const short*)(q31 + (size_t)win * D_ + h * DH_);

    const int k    = lane & 31;
    const int half = lane >> 5;
    const short* krow = (const short*)(kb + (size_t)k * 1024 + half*32);

    float s = 0.f;
    const bf16x8* q8 = (const bf16x8*)(qrow + half*32);
    const bf16x8* k8 = (const bf16x8*)krow;
#pragma unroll
    for (int c = 0; c < 4; ++c) {
        bf16x8 qa = q8[c], kb_ = k8[c];
#pragma unroll
        for (int j = 0; j < 8; ++j) s += bf2f(qa[j]) * bf2f(kb_[j]);
    }
    s += __shfl_xor(s, 32);
    s *= 0.125f;

    float mx = s;
#pragma unroll
    for (int m = 1; m < 32; m <<= 1) mx = fmaxf(mx, __shfl_xor(mx, m));
    float e = __expf(s - mx);
    float sum = e;
#pragma unroll
    for (int m = 1; m < 32; m <<= 1) sum += __shfl_xor(sum, m);
    if (half == 0) Ps[wv][k] = e / sum;
    __syncthreads();

    const short* vb = (const short*)(kb + 512);
    float o = 0.f;
#pragma unroll
    for (int kk = 0; kk < 32; ++kk)
        o += Ps[wv][kk] * bf2f(vb[(size_t)kk * 1024 + lane]);

    ctxl[(size_t)win * D_ + h * DH_ + lane] = __float2bfloat16(o);
}

// ---------------------------------------------------------------------------
// Head: token = xq[n,:] bf16; logits (NWIN,6) then values (NWIN)
// ---------------------------------------------------------------------------
__global__ __launch_bounds__(64) void head_kernel(
    const bf16* __restrict__ xq,
    const float* __restrict__ Wp, const float* __restrict__ bp,
    const float* __restrict__ Wv, const float* __restrict__ bv,
    float* __restrict__ out)
{
    const int n    = blockIdx.x;
    const int lane = threadIdx.x;
    const bf16* row = xq + (size_t)n * D_;
    float t[8];
#pragma unroll
    for (int j = 0; j < 8; ++j) t[j] = bf2f(*(const short*)(row + lane + j*64));

    for (int a = 0; a < A_ + 1; ++a) {
        const float* w = (a < A_) ? (Wp + (size_t)a * D_) : Wv;
        float d = 0.f;
#pragma unroll
        for (int j = 0; j < 8; ++j) d += t[j] * w[lane + j*64];
#pragma unroll
        for (int off = 32; off > 0; off >>= 1) d += __shfl_down(d, off);
        if (lane == 0) {
            if (a < A_) out[(size_t)n*A_ + a] = d + bp[a];
            else        out[(size_t)NWIN*A_ + n] = d + bv[0];
        }
    }
}

// ---------------------------------------------------------------------------
extern "C" void kernel_launch(void* const* d_in, const int* in_sizes, int n_in,
                              void* d_out, int out_size, void* d_ws, size_t ws_size,
                              hipStream_t stream) {
    const float* feats = (const float*)d_in[0];
    const float* pos   = (const float*)d_in[1];
    const float* Wqkv  = (const float*)d_in[2];
    const float* bqkv  = (const float*)d_in[3];
    const float* Wo    = (const float*)d_in[4];
    const float* bo    = (const float*)d_in[5];
    const float* ln1g  = (const float*)d_in[6];
    const float* ln1b  = (const float*)d_in[7];
    const float* W1    = (const float*)d_in[8];
    const float* b1    = (const float*)d_in[9];
    const float* W2    = (const float*)d_in[10];
    const float* b2    = (const float*)d_in[11];
    const float* ln2g  = (const float*)d_in[12];
    const float* ln2b  = (const float*)d_in[13];
    const float* Wp    = (const float*)d_in[14];
    const float* bp    = (const float*)d_in[15];
    const float* Wv    = (const float*)d_in[16];
    const float* bv    = (const float*)d_in[17];
    float* out = (float*)d_out;

    char* basep = (ws_size >= TOTAL_BYTES) ? (char*)d_ws : g_fallback;

    bf16*  xb   = (bf16*)basep;
    bf16*  wq_b = (bf16*)(basep + XB_BYTES);
    bf16*  wo_b = wq_b + WQ_ELEMS;
    bf16*  w1_b = wo_b + WO_ELEMS;
    bf16*  w2_b = w1_b + W1_ELEMS;
    bf16*  fb   = w2_b + W2_ELEMS;                 // (FROWS, 512)
    bf16*  qf   = fb + FB_ELEMS;                   // (FROWS, 1536)
    float* ppb  = (float*)(qf + QF_ELEMS);         // (32, 1536) fp32
    bf16*  scr  = (bf16*)(ppb + PPB_ELEMS);
    bf16*  qkv_s = scr;                            // (NTOK, 1536) attn phase
    bf16*  kv_s  = scr;                            // (NTOK, 1024) layer-3
    bf16*  ctx_s = scr + (size_t)NTOK * (3*D_);    // (NTOK, 512)  attn phase
    bf16*  h_s   = scr;                            // (NTOK, 2048) FFN phase
    bf16*  y_s   = scr + (size_t)NTOK * 2048;      // (NTOK, 512)  both phases
    // layer-3 compact buffers, carved from ctx_s region
    bf16*  ctxl = ctx_s;                           // (NWIN, 512)
    bf16*  ysm  = ctx_s + (size_t)SMALL;           // (NWIN, 512)
    bf16*  hsm  = ctx_s + (size_t)2*SMALL;         // (NWIN, 2048)
    bf16*  xq   = ctx_s + (size_t)6*SMALL;         // (NWIN, 512)
    bf16*  xg   = ctx_s + (size_t)8*SMALL;         // (NWIN, 512) xb rows w=31
    bf16*  q31  = ctx_s + (size_t)9*SMALL;         // (NWIN, 512)

    cvt_kernel<<<(WQ_ELEMS/4 + 255)/256, 256, 0, stream>>>(Wqkv, wq_b, WQ_ELEMS/4);
    cvt_kernel<<<(WO_ELEMS/4 + 255)/256, 256, 0, stream>>>(Wo,   wo_b, WO_ELEMS/4);
    cvt_kernel<<<(W1_ELEMS/4 + 255)/256, 256, 0, stream>>>(W1,   w1_b, W1_ELEMS/4);
    cvt_kernel<<<(W2_ELEMS/4 + 255)/256, 256, 0, stream>>>(W2,   w2_b, W2_ELEMS/4);

    build_x_kernel<<<NTOK * (D_/4) / 256, 256, 0, stream>>>(feats, pos, xb);
    build_fb_kernel<<<FROWS * (D_/4) / 256, 256, 0, stream>>>(feats, pos, fb);

    for (int i = 0; i < L_; ++i) {
        const bf16*  wq_i = wq_b + (size_t)i * 3*D_*D_;
        const float* bq_i = bqkv + (size_t)i * 3*D_;
        const bf16*  wo_i = wo_b + (size_t)i * D_*D_;
        const float* bo_i = bo   + (size_t)i * D_;
        const bf16*  w1_i = w1_b + (size_t)i * 4*D_*D_;
        const float* b1_i = b1   + (size_t)i * 4*D_;
        const bf16*  w2_i = w2_b + (size_t)i * 4*D_*D_;
        const float* b2_i = b2   + (size_t)i * D_;

        if (i == 0) {
            // layer-0 qkv via factors; attention reads qf directly.
            gemm_bf16<false,false,false><<<(FROWS/128) * (3*D_/128), 256, 0, stream>>>(
                fb, wq_i, nullptr, qf, FROWS, 3*D_, D_);
            build_ppb_kernel<<<W_*(3*D_)/256, 256, 0, stream>>>(qf, bq_i, ppb);
            attn_mfma0<<<NWIN * H_ / 4, 256, 0, stream>>>(qf, ppb, ctx_s);
        } else if (i < L_-1) {
            // qkv split into persistent Q (N=512) and KV (N=1024) GEMMs
            // writing one (NTOK,1536) buffer via ldC.
            gemm256m<false,3,2><<<256, 512, 0, stream>>>(
                xb, wq_i, bq_i, qkv_s, 512, 3*D_);
            gemm256m<false,3,4><<<256, 512, 0, stream>>>(
                xb, wq_i + (size_t)D_*D_, bq_i + D_, qkv_s + D_, 1024, 3*D_);
            attn_mfma<<<NWIN * H_ / 4, 256, 0, stream>>>(qkv_s, ctx_s);
        }

        if (i < L_-1) {
            // y = ctx @ Wo^T + bo : N=512, K=512 [persistent]
            gemm256m<false,3,2><<<256, 512, 0, stream>>>(
                ctx_s, wo_i, bo_i, y_s, D_, D_);
            lnres_kernel<<<NTOK/4, 256, 0, stream>>>(
                y_s, xb, xb, ln1g + (size_t)i*D_, ln1b + (size_t)i*D_, D_);
            // h = relu(xb @ W1^T + b1) : N=2048, K=512 [persistent]
            gemm256m<true,3,8><<<256, 512, 0, stream>>>(
                xb, w1_i, b1_i, h_s, 4*D_, 4*D_);
            // y = h @ W2^T + b2 : N=512, K=2048 [persistent]
            gemm256m<false,5,2><<<256, 512, 0, stream>>>(
                h_s, w2_i, b2_i, y_s, D_, D_);
            lnres_kernel<<<NTOK/4, 256, 0, stream>>>(
                y_s, xb, xb, ln2g + (size_t)i*D_, ln2b + (size_t)i*D_, D_);
        } else {
            // last layer: K/V for all tokens (N=1024), Q only at w=31.
            gemm256m<false,3,4><<<256, 512, 0, stream>>>(
                xb, wq_i + (size_t)D_*D_, bq_i + D_, kv_s, 1024, 1024);
            slice31_kernel<<<NWIN*64/256, 256, 0, stream>>>(xb, xg);
            gemm_bf16<false,true,false><<<(NWIN/128) * (D_/128), 256, 0, stream>>>(
                xg, wq_i, bq_i, q31, NWIN, D_, D_);
            attn_last2<<<NWIN * H_ / 4, 256, 0, stream>>>(kv_s, q31, ctxl);
            gemm_bf16<false,true,false><<<(NWIN/128) * (D_/128), 256, 0, stream>>>(
                ctxl, wo_i, bo_i, ysm, NWIN, D_, D_);
            lnres_kernel<<<NWIN/4, 256, 0, stream>>>(
                ysm, xg, xq,
                ln1g + (size_t)i*D_, ln1b + (size_t)i*D_, D_);
            gemm_bf16<true,true,false><<<(NWIN/128) * (4*D_/128), 256, 0, stream>>>(
                xq, w1_i, b1_i, hsm, NWIN, 4*D_, D_);
            gemm_bf16<false,true,false><<<(NWIN/128) * (D_/128), 256, 0, stream>>>(
                hsm, w2_i, b2_i, ysm, NWIN, D_, 4*D_);
            lnres_kernel<<<NWIN/4, 256, 0, stream>>>(
                ysm, xq, xq, ln2g + (size_t)i*D_, ln2b + (size_t)i*D_, D_);
        }
    }

    head_kernel<<<NWIN, 64, 0, stream>>>(xq, Wp, bp, Wv, bv, out);
}